// Round 1
// baseline (2071.075 us; speedup 1.0000x reference)
//
#include <hip/hip_runtime.h>
#include <hip/hip_bf16.h>

#define N_NODES 50000
#define N_EDGES 800000
#define N_PATHS 3
#define IN_F    128
#define HO      256   // H*OUT
#define N_HEADS 4
#define D_HEAD  64
#define HID     128

// ---------------- feat = h @ fc_w[p]  ([N,128] x [128,256]) ----------------
// 16 rows per block staged in LDS; each of 256 threads owns one output col.
__global__ __launch_bounds__(256) void k_feat(const float* __restrict__ h,
                                              const float* __restrict__ fcw,
                                              float* __restrict__ feat) {
    __shared__ float hs[16][IN_F];
    const int row0 = blockIdx.x * 16;
    const int tid  = threadIdx.x;

    const float4* h4  = (const float4*)(h + (size_t)row0 * IN_F);
    float4*       hs4 = (float4*)&hs[0][0];
    for (int i = tid; i < 16 * IN_F / 4; i += 256) hs4[i] = h4[i];
    __syncthreads();

    float acc[16];
#pragma unroll
    for (int r = 0; r < 16; ++r) acc[r] = 0.f;

    for (int k = 0; k < IN_F; ++k) {
        float wk = fcw[k * HO + tid];          // coalesced; L2-resident
#pragma unroll
        for (int r = 0; r < 16; ++r) acc[r] = fmaf(hs[r][k], wk, acc[r]);
    }
#pragma unroll
    for (int r = 0; r < 16; ++r) feat[(size_t)(row0 + r) * HO + tid] = acc[r];
}

// ---------------- el/er: per (node, head) dot with attn vectors ------------
__global__ void k_elr(const float* __restrict__ feat,
                      const float* __restrict__ al, const float* __restrict__ ar,
                      float* __restrict__ el, float* __restrict__ er) {
    int g = blockIdx.x * blockDim.x + threadIdx.x;   // n*4 + h
    if (g >= N_NODES * N_HEADS) return;
    int n = g >> 2, hh = g & 3;
    const float4* f4 = (const float4*)(feat + (size_t)n * HO + hh * D_HEAD);
    const float4* a4 = (const float4*)(al + hh * D_HEAD);
    const float4* b4 = (const float4*)(ar + hh * D_HEAD);
    float sl = 0.f, sr = 0.f;
#pragma unroll
    for (int i = 0; i < D_HEAD / 4; ++i) {
        float4 f = f4[i], a = a4[i], b = b4[i];
        sl += f.x * a.x + f.y * a.y + f.z * a.z + f.w * a.w;
        sr += f.x * b.x + f.y * b.y + f.z * b.z + f.w * b.w;
    }
    el[g] = sl; er[g] = sr;
}

// ---------------- CSR build ------------------------------------------------
__global__ void k_count(const int* __restrict__ dst, int* __restrict__ deg) {
    int e = blockIdx.x * blockDim.x + threadIdx.x;
    if (e < N_EDGES) atomicAdd(&deg[dst[e]], 1);
}

__global__ __launch_bounds__(1024) void k_scan(const int* __restrict__ deg,
                                               int* __restrict__ rowptr,
                                               int* __restrict__ cursor) {
    __shared__ int part[1024];
    const int tid = threadIdx.x;
    const int CH = (N_NODES + 1023) / 1024;       // 49
    const int start = tid * CH;
    int s = 0;
    for (int i = 0; i < CH; ++i) { int idx = start + i; if (idx < N_NODES) s += deg[idx]; }
    part[tid] = s;
    __syncthreads();
    for (int off = 1; off < 1024; off <<= 1) {
        int v = (tid >= off) ? part[tid - off] : 0;
        __syncthreads();
        part[tid] += v;
        __syncthreads();
    }
    int excl = (tid == 0) ? 0 : part[tid - 1];
    for (int i = 0; i < CH; ++i) {
        int idx = start + i;
        if (idx < N_NODES) { rowptr[idx] = excl; cursor[idx] = excl; excl += deg[idx]; }
    }
    if (tid == 1023) rowptr[N_NODES] = N_EDGES;
}

__global__ void k_fill(const int* __restrict__ dst, int* __restrict__ cursor,
                       int* __restrict__ csr) {
    int e = blockIdx.x * blockDim.x + threadIdx.x;
    if (e < N_EDGES) { int p = atomicAdd(&cursor[dst[e]], 1); csr[p] = e; }
}

// ---------------- edge pass: ex = exp(leaky_relu(el[src]+er[dst])), s += ex -
__global__ void k_edge_ex(const int* __restrict__ src, const int* __restrict__ dst,
                          const float* __restrict__ el, const float* __restrict__ er,
                          float* __restrict__ exb, float* __restrict__ sden) {
    int g = blockIdx.x * blockDim.x + threadIdx.x;    // e*4 + h
    if (g >= N_EDGES * N_HEADS) return;
    int e = g >> 2, hh = g & 3;
    int sV = src[e], dV = dst[e];
    float v = el[sV * N_HEADS + hh] + er[dV * N_HEADS + hh];
    v = (v >= 0.f) ? v : 0.2f * v;                    // leaky_relu, slope 0.2
    float x = __expf(v);                              // softmax shift-invariant: no max needed
    exb[g] = x;
    unsafeAtomicAdd(&sden[dV * N_HEADS + hh], x);
}

// ---------------- gather: z[n,p,:] = elu( sum_e alpha_e * feat[src_e,:] ) ---
__global__ __launch_bounds__(256) void k_gather(const int* __restrict__ csr,
                                                const int* __restrict__ rowptr,
                                                const int* __restrict__ src,
                                                const float* __restrict__ exb,
                                                const float* __restrict__ sden,
                                                const float* __restrict__ feat,
                                                float* __restrict__ z /* + p*HO */) {
    const int n  = blockIdx.x;
    const int t  = threadIdx.x;          // col 0..255
    const int hh = t >> 6;
    const int b0 = rowptr[n], b1 = rowptr[n + 1];
    float sd  = sden[n * N_HEADS + hh];
    float inv = (sd > 0.f) ? 1.f / sd : 0.f;
    float acc = 0.f;
    for (int i = b0; i < b1; ++i) {
        int eid = csr[i];                           // wave-uniform (broadcast)
        int sV  = src[eid];
        float a = exb[eid * N_HEADS + hh] * inv;
        acc += feat[(size_t)sV * HO + t] * a;       // contiguous 256B per wave
    }
    float r = (acc > 0.f) ? acc : expm1f(acc);      // elu
    z[(size_t)n * (N_PATHS * HO) + t] = r;
}

// ---------------- semantic attention logits: w = tanh(z@w1+b1)@w2 ----------
__global__ __launch_bounds__(128) void k_sem(const float* __restrict__ z,
                                             const float* __restrict__ w1,
                                             const float* __restrict__ b1,
                                             const float* __restrict__ w2,
                                             float* __restrict__ wsem) {
    __shared__ float zs[8][HO];
    __shared__ float red[8][2];
    const int row0 = blockIdx.x * 8;     // rows are (n*3+p)
    const int j = threadIdx.x;           // col 0..127

    const float4* z4  = (const float4*)(z + (size_t)row0 * HO);
    float4*       zs4 = (float4*)&zs[0][0];
    for (int i = j; i < 8 * HO / 4; i += 128) zs4[i] = z4[i];
    __syncthreads();

    float acc[8];
#pragma unroll
    for (int r = 0; r < 8; ++r) acc[r] = 0.f;
    for (int k = 0; k < HO; ++k) {
        float w = w1[k * HID + j];
#pragma unroll
        for (int r = 0; r < 8; ++r) acc[r] = fmaf(zs[r][k], w, acc[r]);
    }
    float bj = b1[j], wj = w2[j];
#pragma unroll
    for (int r = 0; r < 8; ++r) {
        float v = tanhf(acc[r] + bj) * wj;
        for (int off = 32; off; off >>= 1) v += __shfl_down(v, off, 64);
        if ((j & 63) == 0) red[r][j >> 6] = v;
    }
    __syncthreads();
    if (j < 8) wsem[row0 + j] = red[j][0] + red[j][1];
}

// ---------------- final: softmax over P, weighted sum -----------------------
__global__ __launch_bounds__(256) void k_out(const float* __restrict__ z,
                                             const float* __restrict__ wsem,
                                             float* __restrict__ out) {
    const int n = blockIdx.x, t = threadIdx.x;
    float w0 = wsem[n * 3 + 0], w1v = wsem[n * 3 + 1], w2v = wsem[n * 3 + 2];
    float mx = fmaxf(w0, fmaxf(w1v, w2v));
    float e0 = __expf(w0 - mx), e1 = __expf(w1v - mx), e2 = __expf(w2v - mx);
    float is = 1.f / (e0 + e1 + e2);
    const float* zr = z + (size_t)n * (N_PATHS * HO);
    out[(size_t)n * HO + t] = (e0 * zr[t] + e1 * zr[HO + t] + e2 * zr[2 * HO + t]) * is;
}

// ---------------------------------------------------------------------------
static inline size_t align256(size_t x) { return (x + 255) & ~(size_t)255; }

extern "C" void kernel_launch(void* const* d_in, const int* in_sizes, int n_in,
                              void* d_out, int out_size, void* d_ws, size_t ws_size,
                              hipStream_t stream) {
    const float* h     = (const float*)d_in[0];
    const int*   edges = (const int*)d_in[1];     // [P,2,E]
    const float* fc_w  = (const float*)d_in[2];   // [P,128,256]
    const float* al    = (const float*)d_in[3];   // [P,4,64]
    const float* ar    = (const float*)d_in[4];
    const float* w1    = (const float*)d_in[5];   // [256,128]
    const float* b1    = (const float*)d_in[6];   // [128]
    const float* w2    = (const float*)d_in[7];   // [128]
    float* out = (float*)d_out;

    char* base = (char*)d_ws;
    size_t off = 0;
    auto carve = [&](size_t bytes) -> char* {
        char* p = base + off; off = align256(off + bytes); return p;
    };
    float* feat   = (float*)carve((size_t)N_NODES * HO * 4);            // 51.2 MB (reused per path)
    float* z      = (float*)carve((size_t)N_NODES * N_PATHS * HO * 4);  // 153.6 MB
    float* exb    = (float*)carve((size_t)N_EDGES * N_HEADS * 4);       // 12.8 MB
    float* el     = (float*)carve((size_t)N_NODES * N_HEADS * 4);
    float* er     = (float*)carve((size_t)N_NODES * N_HEADS * 4);
    float* sden   = (float*)carve((size_t)N_NODES * N_HEADS * 4);
    float* wsem   = (float*)carve((size_t)N_NODES * N_PATHS * 4);
    int*   deg    = (int*)carve((size_t)N_NODES * 4);
    int*   rowptr = (int*)carve((size_t)(N_NODES + 1) * 4);
    int*   cursor = (int*)carve((size_t)N_NODES * 4);
    int*   csr    = (int*)carve((size_t)N_EDGES * 4);
    (void)ws_size; (void)in_sizes; (void)n_in; (void)out_size;

    for (int p = 0; p < N_PATHS; ++p) {
        const int* src = edges + (size_t)p * 2 * N_EDGES;
        const int* dst = src + N_EDGES;

        k_feat<<<N_NODES / 16, 256, 0, stream>>>(h, fc_w + (size_t)p * IN_F * HO, feat);
        k_elr<<<(N_NODES * N_HEADS + 255) / 256, 256, 0, stream>>>(
            feat, al + p * N_HEADS * D_HEAD, ar + p * N_HEADS * D_HEAD, el, er);

        hipMemsetAsync(deg, 0, N_NODES * 4, stream);
        hipMemsetAsync(sden, 0, N_NODES * N_HEADS * 4, stream);

        k_count<<<(N_EDGES + 255) / 256, 256, 0, stream>>>(dst, deg);
        k_edge_ex<<<(N_EDGES * N_HEADS + 255) / 256, 256, 0, stream>>>(
            src, dst, el, er, exb, sden);
        k_scan<<<1, 1024, 0, stream>>>(deg, rowptr, cursor);
        k_fill<<<(N_EDGES + 255) / 256, 256, 0, stream>>>(dst, cursor, csr);
        k_gather<<<N_NODES, 256, 0, stream>>>(csr, rowptr, src, exb, sden, feat, z + p * HO);
    }
    k_sem<<<(N_NODES * N_PATHS) / 8, 128, 0, stream>>>(z, w1, b1, w2, wsem);
    k_out<<<N_NODES, 256, 0, stream>>>(z, wsem, out);
}

// Round 2
// 1337.686 us; speedup vs baseline: 1.5483x; 1.5483x over previous
//
#include <hip/hip_runtime.h>
#include <hip/hip_bf16.h>

#define N_NODES 50000
#define N_EDGES 800000
#define N_PATHS 3
#define IN_F    128
#define HO      256   // H*OUT
#define N_HEADS 4
#define D_HEAD  64
#define HID     128

// ---- feat = h @ fc_w[p]  + fused el/er ------------------------------------
// 16 rows staged in LDS; thread t owns output col t; wave hh == head hh.
__global__ __launch_bounds__(256) void k_feat(const float* __restrict__ h,
                                              const float* __restrict__ fcw,
                                              const float* __restrict__ al,
                                              const float* __restrict__ ar,
                                              float* __restrict__ feat,
                                              float* __restrict__ el,
                                              float* __restrict__ er) {
    __shared__ float hs[16][IN_F];
    const int row0 = blockIdx.x * 16;
    const int t    = threadIdx.x;

    const float4* h4  = (const float4*)(h + (size_t)row0 * IN_F);
    float4*       hs4 = (float4*)&hs[0][0];
    for (int i = t; i < 16 * IN_F / 4; i += 256) hs4[i] = h4[i];
    __syncthreads();

    float acc[16];
#pragma unroll
    for (int r = 0; r < 16; ++r) acc[r] = 0.f;
    for (int k = 0; k < IN_F; ++k) {
        float wk = fcw[k * HO + t];
#pragma unroll
        for (int r = 0; r < 16; ++r) acc[r] = fmaf(hs[r][k], wk, acc[r]);
    }
#pragma unroll
    for (int r = 0; r < 16; ++r) feat[(size_t)(row0 + r) * HO + t] = acc[r];

    // el[n,h] = sum_d feat[n, h*64+d]*al[h,d]  (wave = head, lane = d)
    const int hh = t >> 6, c = t & 63;
    const float alc = al[hh * D_HEAD + c];
    const float arc = ar[hh * D_HEAD + c];
#pragma unroll
    for (int r = 0; r < 16; ++r) {
        float vl = acc[r] * alc, vr = acc[r] * arc;
#pragma unroll
        for (int off = 32; off; off >>= 1) {
            vl += __shfl_down(vl, off, 64);
            vr += __shfl_down(vr, off, 64);
        }
        if (c == 0) {
            el[(row0 + r) * N_HEADS + hh] = vl;
            er[(row0 + r) * N_HEADS + hh] = vr;
        }
    }
}

// ---- batched CSR build over all paths --------------------------------------
__global__ void k_count(const int* __restrict__ edges, int* __restrict__ deg) {
    int g = blockIdx.x * blockDim.x + threadIdx.x;
    if (g >= N_PATHS * N_EDGES) return;
    int p = g / N_EDGES, e = g - p * N_EDGES;
    const int d = edges[(size_t)p * 2 * N_EDGES + N_EDGES + e];
    atomicAdd(&deg[p * N_NODES + d], 1);
}

__global__ __launch_bounds__(1024) void k_scan(const int* __restrict__ deg,
                                               int* __restrict__ rowptr,
                                               int* __restrict__ cursor) {
    __shared__ int part[1024];
    const int p = blockIdx.x;
    const int* dg = deg + p * N_NODES;
    int* rp = rowptr + p * (N_NODES + 1);
    int* cu = cursor + p * N_NODES;

    const int tid = threadIdx.x;
    const int CH = (N_NODES + 1023) / 1024;       // 49
    const int start = tid * CH;
    int s = 0;
    for (int i = 0; i < CH; ++i) { int idx = start + i; if (idx < N_NODES) s += dg[idx]; }
    part[tid] = s;
    __syncthreads();
    for (int off = 1; off < 1024; off <<= 1) {
        int v = (tid >= off) ? part[tid - off] : 0;
        __syncthreads();
        part[tid] += v;
        __syncthreads();
    }
    int excl = (tid == 0) ? 0 : part[tid - 1];
    for (int i = 0; i < CH; ++i) {
        int idx = start + i;
        if (idx < N_NODES) { rp[idx] = excl; cu[idx] = excl; excl += dg[idx]; }
    }
    if (tid == 1023) rp[N_NODES] = N_EDGES;
}

__global__ void k_fill(const int* __restrict__ edges, int* __restrict__ cursor,
                       int* __restrict__ csr) {
    int g = blockIdx.x * blockDim.x + threadIdx.x;
    if (g >= N_PATHS * N_EDGES) return;
    int p = g / N_EDGES, e = g - p * N_EDGES;
    const int d = edges[(size_t)p * 2 * N_EDGES + N_EDGES + e];
    int pos = atomicAdd(&cursor[p * N_NODES + d], 1);
    csr[(size_t)p * N_EDGES + pos] = e;
}

// ---- gather: stage(ex,src) in LDS -> 4-wave float4 accumulate --------------
__global__ __launch_bounds__(256) void k_gather(const int* __restrict__ csr,
                                                const int* __restrict__ rowptr,
                                                const int* __restrict__ src,
                                                const float* __restrict__ el,
                                                const float* __restrict__ er,
                                                const float* __restrict__ feat,
                                                float* __restrict__ z /* + p*HO */) {
    __shared__ int    s_lds[256];
    __shared__ float4 a_lds[256];
    __shared__ float  den[N_HEADS];
    __shared__ float  red[4][HO];

    const int n = blockIdx.x;
    const int t = threadIdx.x;
    const int w = t >> 6, l = t & 63;
    const int b0 = rowptr[n], b1 = rowptr[n + 1];
    const int deg = b1 - b0;

    if (t < N_HEADS) den[t] = 0.f;
    const float4 er_n = ((const float4*)er)[n];    // uniform per block

    float4 acc = {0.f, 0.f, 0.f, 0.f};

    for (int base = 0; base < deg; base += 256) {
        const int cnt = min(256, deg - base);
        __syncthreads();                            // s_lds/a_lds free to rewrite
        float4 ex4 = {0.f, 0.f, 0.f, 0.f};
        if (t < cnt) {
            int eid = csr[b0 + base + t];
            int sV  = src[eid];
            s_lds[t] = sV;
            float4 e4 = ((const float4*)el)[sV];
            float vx = e4.x + er_n.x, vy = e4.y + er_n.y,
                  vz = e4.z + er_n.z, vw = e4.w + er_n.w;
            vx = (vx >= 0.f) ? vx : 0.2f * vx;
            vy = (vy >= 0.f) ? vy : 0.2f * vy;
            vz = (vz >= 0.f) ? vz : 0.2f * vz;
            vw = (vw >= 0.f) ? vw : 0.2f * vw;
            ex4 = make_float4(__expf(vx), __expf(vy), __expf(vz), __expf(vw));
            a_lds[t] = ex4;
        }
        // denominator partials: wave reduce then LDS atomic
#pragma unroll
        for (int off = 32; off; off >>= 1) {
            ex4.x += __shfl_down(ex4.x, off, 64);
            ex4.y += __shfl_down(ex4.y, off, 64);
            ex4.z += __shfl_down(ex4.z, off, 64);
            ex4.w += __shfl_down(ex4.w, off, 64);
        }
        if (l == 0) {
            atomicAdd(&den[0], ex4.x); atomicAdd(&den[1], ex4.y);
            atomicAdd(&den[2], ex4.z); atomicAdd(&den[3], ex4.w);
        }
        __syncthreads();                            // staging visible
        // accumulate: wave w takes edges base+w, base+w+4, ...
        const float* a_f = (const float*)a_lds;
        for (int i = w; i < cnt; i += 4) {
            int sV  = s_lds[i];                     // wave-uniform broadcast
            float a = a_f[i * 4 + (l >> 4)];
            float4 f = ((const float4*)feat)[(size_t)sV * 64 + l];
            acc.x = fmaf(f.x, a, acc.x);
            acc.y = fmaf(f.y, a, acc.y);
            acc.z = fmaf(f.z, a, acc.z);
            acc.w = fmaf(f.w, a, acc.w);
        }
    }

    __syncthreads();
    *(float4*)&red[w][4 * l] = acc;
    __syncthreads();
    float tot = red[0][t] + red[1][t] + red[2][t] + red[3][t];
    float dv  = den[t >> 6];
    float inv = (dv > 0.f) ? 1.f / dv : 0.f;
    float r   = tot * inv;
    r = (r > 0.f) ? r : expm1f(r);                  // elu
    z[(size_t)n * (N_PATHS * HO) + t] = r;
}

// ---- semantic attention logits: w = tanh(z@w1+b1)@w2 -----------------------
__global__ __launch_bounds__(128) void k_sem(const float* __restrict__ z,
                                             const float* __restrict__ w1,
                                             const float* __restrict__ b1,
                                             const float* __restrict__ w2,
                                             float* __restrict__ wsem) {
    __shared__ float zs[16][HO];
    __shared__ float red[16][2];
    const int row0 = blockIdx.x * 16;    // rows are (n*3+p)
    const int j = threadIdx.x;           // col 0..127

    const float4* z4  = (const float4*)(z + (size_t)row0 * HO);
    float4*       zs4 = (float4*)&zs[0][0];
    for (int i = j; i < 16 * HO / 4; i += 128) zs4[i] = z4[i];
    __syncthreads();

    float acc[16];
#pragma unroll
    for (int r = 0; r < 16; ++r) acc[r] = 0.f;
    for (int k = 0; k < HO; ++k) {
        float w = w1[k * HID + j];
#pragma unroll
        for (int r = 0; r < 16; ++r) acc[r] = fmaf(zs[r][k], w, acc[r]);
    }
    float bj = b1[j], wj = w2[j];
#pragma unroll
    for (int r = 0; r < 16; ++r) {
        float v = tanhf(acc[r] + bj) * wj;
#pragma unroll
        for (int off = 32; off; off >>= 1) v += __shfl_down(v, off, 64);
        if ((j & 63) == 0) red[r][j >> 6] = v;
    }
    __syncthreads();
    if (j < 16) wsem[row0 + j] = red[j][0] + red[j][1];
}

// ---- final: softmax over P, weighted sum -----------------------------------
__global__ __launch_bounds__(256) void k_out(const float* __restrict__ z,
                                             const float* __restrict__ wsem,
                                             float* __restrict__ out) {
    const int n = blockIdx.x, t = threadIdx.x;
    float w0 = wsem[n * 3 + 0], w1v = wsem[n * 3 + 1], w2v = wsem[n * 3 + 2];
    float mx = fmaxf(w0, fmaxf(w1v, w2v));
    float e0 = __expf(w0 - mx), e1 = __expf(w1v - mx), e2 = __expf(w2v - mx);
    float is = 1.f / (e0 + e1 + e2);
    const float* zr = z + (size_t)n * (N_PATHS * HO);
    out[(size_t)n * HO + t] = (e0 * zr[t] + e1 * zr[HO + t] + e2 * zr[2 * HO + t]) * is;
}

// ---------------------------------------------------------------------------
static inline size_t align256(size_t x) { return (x + 255) & ~(size_t)255; }

extern "C" void kernel_launch(void* const* d_in, const int* in_sizes, int n_in,
                              void* d_out, int out_size, void* d_ws, size_t ws_size,
                              hipStream_t stream) {
    const float* h     = (const float*)d_in[0];
    const int*   edges = (const int*)d_in[1];     // [P,2,E]
    const float* fc_w  = (const float*)d_in[2];   // [P,128,256]
    const float* al    = (const float*)d_in[3];   // [P,4,64]
    const float* ar    = (const float*)d_in[4];
    const float* w1    = (const float*)d_in[5];   // [256,128]
    const float* b1    = (const float*)d_in[6];   // [128]
    const float* w2    = (const float*)d_in[7];   // [128]
    float* out = (float*)d_out;

    char* base = (char*)d_ws;
    size_t off = 0;
    auto carve = [&](size_t bytes) -> char* {
        char* p = base + off; off = align256(off + bytes); return p;
    };
    float* feat   = (float*)carve((size_t)N_NODES * HO * 4);            // 51.2 MB (per-path reuse)
    float* z      = (float*)carve((size_t)N_NODES * N_PATHS * HO * 4);  // 153.6 MB
    float* el     = (float*)carve((size_t)N_NODES * N_HEADS * 4);
    float* er     = (float*)carve((size_t)N_NODES * N_HEADS * 4);
    float* wsem   = (float*)carve((size_t)N_NODES * N_PATHS * 4);
    int*   deg    = (int*)carve((size_t)N_PATHS * N_NODES * 4);
    int*   rowptr = (int*)carve((size_t)N_PATHS * (N_NODES + 1) * 4);
    int*   cursor = (int*)carve((size_t)N_PATHS * N_NODES * 4);
    int*   csr    = (int*)carve((size_t)N_PATHS * N_EDGES * 4);         // 9.6 MB
    (void)ws_size; (void)in_sizes; (void)n_in; (void)out_size;

    // batched CSR build (independent of features)
    hipMemsetAsync(deg, 0, (size_t)N_PATHS * N_NODES * 4, stream);
    k_count<<<(N_PATHS * N_EDGES + 255) / 256, 256, 0, stream>>>(edges, deg);
    k_scan<<<N_PATHS, 1024, 0, stream>>>(deg, rowptr, cursor);
    k_fill<<<(N_PATHS * N_EDGES + 255) / 256, 256, 0, stream>>>(edges, cursor, csr);

    for (int p = 0; p < N_PATHS; ++p) {
        const int* src = edges + (size_t)p * 2 * N_EDGES;
        k_feat<<<N_NODES / 16, 256, 0, stream>>>(
            h, fc_w + (size_t)p * IN_F * HO,
            al + p * N_HEADS * D_HEAD, ar + p * N_HEADS * D_HEAD, feat, el, er);
        k_gather<<<N_NODES, 256, 0, stream>>>(
            csr + (size_t)p * N_EDGES, rowptr + p * (N_NODES + 1), src,
            el, er, feat, z + p * HO);
    }
    k_sem<<<(N_NODES * N_PATHS + 15) / 16, 128, 0, stream>>>(z, w1, b1, w2, wsem);
    k_out<<<N_NODES, 256, 0, stream>>>(z, wsem, out);
}

// Round 3
// 1026.693 us; speedup vs baseline: 2.0172x; 1.3029x over previous
//
#include <hip/hip_runtime.h>
#include <hip/hip_bf16.h>

#define N_NODES 50000
#define N_EDGES 800000
#define N_PATHS 3
#define IN_F    128
#define HO      256   // H*OUT
#define N_HEADS 4
#define D_HEAD  64
#define HID     128

typedef __bf16 bf16;
typedef __bf16 bf16x4 __attribute__((ext_vector_type(4)));
typedef __bf16 bf16x8 __attribute__((ext_vector_type(8)));
typedef float  f32x4  __attribute__((ext_vector_type(4)));

// ---- feat = h @ fc_w[p] (fp32 compute, bf16 store) + fused el/er -----------
__global__ __launch_bounds__(256) void k_feat(const float* __restrict__ h,
                                              const float* __restrict__ fcw,
                                              const float* __restrict__ al,
                                              const float* __restrict__ ar,
                                              bf16* __restrict__ feat,
                                              float* __restrict__ el,
                                              float* __restrict__ er) {
    __shared__ float hs[16][IN_F];
    const int row0 = blockIdx.x * 16;
    const int t    = threadIdx.x;

    const float4* h4  = (const float4*)(h + (size_t)row0 * IN_F);
    float4*       hs4 = (float4*)&hs[0][0];
    for (int i = t; i < 16 * IN_F / 4; i += 256) hs4[i] = h4[i];
    __syncthreads();

    float acc[16];
#pragma unroll
    for (int r = 0; r < 16; ++r) acc[r] = 0.f;
    for (int k = 0; k < IN_F; ++k) {
        float wk = fcw[k * HO + t];
#pragma unroll
        for (int r = 0; r < 16; ++r) acc[r] = fmaf(hs[r][k], wk, acc[r]);
    }
#pragma unroll
    for (int r = 0; r < 16; ++r)
        feat[(size_t)(row0 + r) * HO + t] = (bf16)acc[r];

    // el[n,h] = sum_d feat[n,h*64+d]*al[h,d]  (wave = head, lane = d), fp32
    const int hh = t >> 6, c = t & 63;
    const float alc = al[hh * D_HEAD + c];
    const float arc = ar[hh * D_HEAD + c];
#pragma unroll
    for (int r = 0; r < 16; ++r) {
        float vl = acc[r] * alc, vr = acc[r] * arc;
#pragma unroll
        for (int off = 32; off; off >>= 1) {
            vl += __shfl_down(vl, off, 64);
            vr += __shfl_down(vr, off, 64);
        }
        if (c == 0) {
            el[(row0 + r) * N_HEADS + hh] = vl;
            er[(row0 + r) * N_HEADS + hh] = vr;
        }
    }
}

// ---- batched CSR build over all paths --------------------------------------
__global__ void k_count(const int* __restrict__ edges, int* __restrict__ deg) {
    int g = blockIdx.x * blockDim.x + threadIdx.x;
    if (g >= N_PATHS * N_EDGES) return;
    int p = g / N_EDGES, e = g - p * N_EDGES;
    const int d = edges[(size_t)p * 2 * N_EDGES + N_EDGES + e];
    atomicAdd(&deg[p * N_NODES + d], 1);
}

__global__ __launch_bounds__(1024) void k_scan(const int* __restrict__ deg,
                                               int* __restrict__ rowptr,
                                               int* __restrict__ cursor) {
    __shared__ int part[1024];
    const int p = blockIdx.x;
    const int* dg = deg + p * N_NODES;
    int* rp = rowptr + p * (N_NODES + 1);
    int* cu = cursor + p * N_NODES;

    const int tid = threadIdx.x;
    const int CH = (N_NODES + 1023) / 1024;       // 49
    const int start = tid * CH;
    int s = 0;
    for (int i = 0; i < CH; ++i) { int idx = start + i; if (idx < N_NODES) s += dg[idx]; }
    part[tid] = s;
    __syncthreads();
    for (int off = 1; off < 1024; off <<= 1) {
        int v = (tid >= off) ? part[tid - off] : 0;
        __syncthreads();
        part[tid] += v;
        __syncthreads();
    }
    int excl = (tid == 0) ? 0 : part[tid - 1];
    for (int i = 0; i < CH; ++i) {
        int idx = start + i;
        if (idx < N_NODES) { rp[idx] = excl; cu[idx] = excl; excl += dg[idx]; }
    }
    if (tid == 1023) rp[N_NODES] = N_EDGES;
}

__global__ void k_fill(const int* __restrict__ edges, int* __restrict__ cursor,
                       int* __restrict__ csr) {
    int g = blockIdx.x * blockDim.x + threadIdx.x;
    if (g >= N_PATHS * N_EDGES) return;
    int p = g / N_EDGES, e = g - p * N_EDGES;
    const int d = edges[(size_t)p * 2 * N_EDGES + N_EDGES + e];
    int pos = atomicAdd(&cursor[p * N_NODES + d], 1);
    csr[(size_t)p * N_EDGES + pos] = e;
}

// ---- gather: one wave per node, no barriers, no atomics --------------------
__global__ __launch_bounds__(256) void k_gather(const int* __restrict__ csr,
                                                const int* __restrict__ rowptr,
                                                const int* __restrict__ src,
                                                const float4* __restrict__ el4,
                                                const float4* __restrict__ er4,
                                                const bf16* __restrict__ feat,
                                                float* __restrict__ z /* + p*HO */) {
    __shared__ float exbuf[4][64 * N_HEADS];       // per-wave ex staging
    const int wid = threadIdx.x >> 6, l = threadIdx.x & 63;
    const int n = blockIdx.x * 4 + wid;            // 50000 % 4 == 0

    const int b0 = rowptr[n], b1 = rowptr[n + 1];
    const float4 er_n = er4[n];
    float* exw = exbuf[wid];

    float4 acc = {0.f, 0.f, 0.f, 0.f};
    float4 den = {0.f, 0.f, 0.f, 0.f};

    for (int base = b0; base < b1; base += 64) {
        const int cnt = min(64, b1 - base);
        int sv = 0;
        if (l < cnt) {
            int eid = csr[base + l];
            sv = src[eid];
            float4 e = el4[sv];
            float vx = e.x + er_n.x, vy = e.y + er_n.y,
                  vz = e.z + er_n.z, vw = e.w + er_n.w;
            vx = (vx >= 0.f) ? vx : 0.2f * vx;
            vy = (vy >= 0.f) ? vy : 0.2f * vy;
            vz = (vz >= 0.f) ? vz : 0.2f * vz;
            vw = (vw >= 0.f) ? vw : 0.2f * vw;
            float4 ex = make_float4(__expf(vx), __expf(vy), __expf(vz), __expf(vw));
            *(float4*)&exw[l * 4] = ex;
            den.x += ex.x; den.y += ex.y; den.z += ex.z; den.w += ex.w;
        }
        // accumulate: lane l owns cols 4l..4l+3 (head l>>4); wave reads 512B/edge
        const int hh = l >> 4;
        for (int i = 0; i < cnt; ++i) {
            int sV  = __shfl(sv, i, 64);
            float a = exw[i * 4 + hh];             // 4-addr broadcast
            bf16x4 f = *(const bf16x4*)(feat + (size_t)sV * HO + l * 4);
            acc.x = fmaf((float)f[0], a, acc.x);
            acc.y = fmaf((float)f[1], a, acc.y);
            acc.z = fmaf((float)f[2], a, acc.z);
            acc.w = fmaf((float)f[3], a, acc.w);
        }
    }

    // denominator: butterfly over full wave (per-lane partials -> total)
#pragma unroll
    for (int off = 32; off; off >>= 1) {
        den.x += __shfl_xor(den.x, off, 64);
        den.y += __shfl_xor(den.y, off, 64);
        den.z += __shfl_xor(den.z, off, 64);
        den.w += __shfl_xor(den.w, off, 64);
    }
    const int hh = l >> 4;
    float d = (hh == 0) ? den.x : (hh == 1) ? den.y : (hh == 2) ? den.z : den.w;
    float inv = (d > 0.f) ? 1.f / d : 0.f;
    float4 r;
    r.x = acc.x * inv; r.y = acc.y * inv; r.z = acc.z * inv; r.w = acc.w * inv;
    r.x = (r.x > 0.f) ? r.x : expm1f(r.x);
    r.y = (r.y > 0.f) ? r.y : expm1f(r.y);
    r.z = (r.z > 0.f) ? r.z : expm1f(r.z);
    r.w = (r.w > 0.f) ? r.w : expm1f(r.w);
    *(float4*)&z[(size_t)n * (N_PATHS * HO) + l * 4] = r;
}

// ---- fused semantic attention + output: MFMA logits, fp32 combine ----------
// 16 nodes (48 z-rows) per block; z staged fp32 in LDS (stride 260 floats).
__global__ __launch_bounds__(256) void k_semout(const float* __restrict__ z,
                                                const float* __restrict__ w1,
                                                const float* __restrict__ b1,
                                                const float* __restrict__ w2,
                                                float* __restrict__ out) {
    __shared__ float zs[48 * 260];                 // 49,920 B, 2-way conflicts only
    __shared__ float psem[4][48];
    __shared__ float betas[16][4];

    const int t = threadIdx.x, w = t >> 6, l = t & 63;
    const int lo = l & 15, hi = l >> 4;
    const int n0 = blockIdx.x * 16;
    const float* zg = z + (size_t)n0 * (N_PATHS * HO);

    // B-frag preload (overlaps with staging): wave w covers col-tiles 2w,2w+1
    bf16x8 bfr[2][8];
#pragma unroll
    for (int ct = 0; ct < 2; ++ct) {
        const int j = (2 * w + ct) * 16 + lo;
#pragma unroll
        for (int s = 0; s < 8; ++s) {
            const int k0 = s * 32 + hi * 8;
            bf16x8 b;
#pragma unroll
            for (int i = 0; i < 8; ++i) b[i] = (bf16)w1[(k0 + i) * HID + j];
            bfr[ct][s] = b;
        }
    }

    // stage 48 rows x 256 cols (contiguous in z) into padded LDS
    for (int i = t; i < 48 * 64; i += 256) {
        float4 v = ((const float4*)zg)[i];
        int r = i >> 6, c = (i & 63) << 2;
        *(float4*)&zs[r * 260 + c] = v;
    }
    __syncthreads();

    f32x4 acc[2][3];
#pragma unroll
    for (int ct = 0; ct < 2; ++ct)
#pragma unroll
        for (int m = 0; m < 3; ++m) { f32x4 zz = {0.f,0.f,0.f,0.f}; acc[ct][m] = zz; }

    for (int s = 0; s < 8; ++s) {
#pragma unroll
        for (int m = 0; m < 3; ++m) {
            const float* ap = &zs[(m * 16 + lo) * 260 + s * 32 + hi * 8];
            float4 f0 = *(const float4*)ap;
            float4 f1 = *(const float4*)(ap + 4);
            bf16x8 a;
            a[0]=(bf16)f0.x; a[1]=(bf16)f0.y; a[2]=(bf16)f0.z; a[3]=(bf16)f0.w;
            a[4]=(bf16)f1.x; a[5]=(bf16)f1.y; a[6]=(bf16)f1.z; a[7]=(bf16)f1.w;
            acc[0][m] = __builtin_amdgcn_mfma_f32_16x16x32_bf16(a, bfr[0][s], acc[0][m], 0, 0, 0);
            acc[1][m] = __builtin_amdgcn_mfma_f32_16x16x32_bf16(a, bfr[1][s], acc[1][m], 0, 0, 0);
        }
    }

    // epilogue: tanh(acc + b1)*w2, reduce over cols (lane bits 0..3)
    const int j0 = (2 * w + 0) * 16 + lo;
    const int j1 = (2 * w + 1) * 16 + lo;
    const float b1_0 = b1[j0], w2_0 = w2[j0];
    const float b1_1 = b1[j1], w2_1 = w2[j1];
#pragma unroll
    for (int m = 0; m < 3; ++m) {
#pragma unroll
        for (int r = 0; r < 4; ++r) {
            float tt = tanhf(acc[0][m][r] + b1_0) * w2_0
                     + tanhf(acc[1][m][r] + b1_1) * w2_1;
            tt += __shfl_xor(tt, 1, 64);
            tt += __shfl_xor(tt, 2, 64);
            tt += __shfl_xor(tt, 4, 64);
            tt += __shfl_xor(tt, 8, 64);
            if (lo == 0) psem[w][m * 16 + hi * 4 + r] = tt;
        }
    }
    __syncthreads();
    if (t < 48) psem[0][t] = psem[0][t] + psem[1][t] + psem[2][t] + psem[3][t];
    __syncthreads();
    if (t < 16) {
        float a0 = psem[0][3 * t], a1 = psem[0][3 * t + 1], a2 = psem[0][3 * t + 2];
        float mx = fmaxf(a0, fmaxf(a1, a2));
        float e0 = __expf(a0 - mx), e1 = __expf(a1 - mx), e2 = __expf(a2 - mx);
        float is = 1.f / (e0 + e1 + e2);
        betas[t][0] = e0 * is; betas[t][1] = e1 * is; betas[t][2] = e2 * is;
    }
    __syncthreads();
    // combine from fp32 LDS copy
    for (int i = 0; i < 16; ++i) {
        float bb0 = betas[i][0], bb1 = betas[i][1], bb2 = betas[i][2];
        float o = bb0 * zs[(3 * i + 0) * 260 + t]
                + bb1 * zs[(3 * i + 1) * 260 + t]
                + bb2 * zs[(3 * i + 2) * 260 + t];
        out[(size_t)(n0 + i) * HO + t] = o;
    }
}

// ---------------------------------------------------------------------------
static inline size_t align256(size_t x) { return (x + 255) & ~(size_t)255; }

extern "C" void kernel_launch(void* const* d_in, const int* in_sizes, int n_in,
                              void* d_out, int out_size, void* d_ws, size_t ws_size,
                              hipStream_t stream) {
    const float* h     = (const float*)d_in[0];
    const int*   edges = (const int*)d_in[1];     // [P,2,E]
    const float* fc_w  = (const float*)d_in[2];   // [P,128,256]
    const float* al    = (const float*)d_in[3];   // [P,4,64]
    const float* ar    = (const float*)d_in[4];
    const float* w1    = (const float*)d_in[5];   // [256,128]
    const float* b1    = (const float*)d_in[6];   // [128]
    const float* w2    = (const float*)d_in[7];   // [128]
    float* out = (float*)d_out;

    char* base = (char*)d_ws;
    size_t off = 0;
    auto carve = [&](size_t bytes) -> char* {
        char* p = base + off; off = align256(off + bytes); return p;
    };
    bf16*  feat   = (bf16*)carve((size_t)N_NODES * HO * 2);             // 25.6 MB (per-path reuse)
    float* z      = (float*)carve((size_t)N_NODES * N_PATHS * HO * 4);  // 153.6 MB
    float* el     = (float*)carve((size_t)N_NODES * N_HEADS * 4);
    float* er     = (float*)carve((size_t)N_NODES * N_HEADS * 4);
    int*   deg    = (int*)carve((size_t)N_PATHS * N_NODES * 4);
    int*   rowptr = (int*)carve((size_t)N_PATHS * (N_NODES + 1) * 4);
    int*   cursor = (int*)carve((size_t)N_PATHS * N_NODES * 4);
    int*   csr    = (int*)carve((size_t)N_PATHS * N_EDGES * 4);         // 9.6 MB
    (void)ws_size; (void)in_sizes; (void)n_in; (void)out_size;

    // batched CSR build (independent of features)
    hipMemsetAsync(deg, 0, (size_t)N_PATHS * N_NODES * 4, stream);
    k_count<<<(N_PATHS * N_EDGES + 255) / 256, 256, 0, stream>>>(edges, deg);
    k_scan<<<N_PATHS, 1024, 0, stream>>>(deg, rowptr, cursor);
    k_fill<<<(N_PATHS * N_EDGES + 255) / 256, 256, 0, stream>>>(edges, cursor, csr);

    for (int p = 0; p < N_PATHS; ++p) {
        const int* src = edges + (size_t)p * 2 * N_EDGES;
        k_feat<<<N_NODES / 16, 256, 0, stream>>>(
            h, fc_w + (size_t)p * IN_F * HO,
            al + p * N_HEADS * D_HEAD, ar + p * N_HEADS * D_HEAD, feat, el, er);
        k_gather<<<N_NODES / 4, 256, 0, stream>>>(
            csr + (size_t)p * N_EDGES, rowptr + p * (N_NODES + 1), src,
            (const float4*)el, (const float4*)er, feat, z + p * HO);
    }
    k_semout<<<N_NODES / 16, 256, 0, stream>>>(z, w1, b1, w2, out);
}

// Round 4
// 827.990 us; speedup vs baseline: 2.5013x; 1.2400x over previous
//
#include <hip/hip_runtime.h>
#include <hip/hip_bf16.h>

#define N_NODES 50000
#define N_EDGES 800000
#define N_PATHS 3
#define IN_F    128
#define HO      256   // H*OUT
#define N_HEADS 4
#define D_HEAD  64
#define HID     128

typedef __bf16 bf16;
typedef __bf16 bf16x4 __attribute__((ext_vector_type(4)));
typedef __bf16 bf16x8 __attribute__((ext_vector_type(8)));
typedef float  f32x4  __attribute__((ext_vector_type(4)));

// ---- feat = h @ fc_w[p] (fp32 compute, bf16 store) + fused el/er -----------
__global__ __launch_bounds__(256) void k_feat(const float* __restrict__ h,
                                              const float* __restrict__ fcw,
                                              const float* __restrict__ al,
                                              const float* __restrict__ ar,
                                              bf16* __restrict__ feat,
                                              float* __restrict__ el,
                                              float* __restrict__ er) {
    __shared__ float hs[16][IN_F];
    const int row0 = blockIdx.x * 16;
    const int t    = threadIdx.x;

    const float4* h4  = (const float4*)(h + (size_t)row0 * IN_F);
    float4*       hs4 = (float4*)&hs[0][0];
    for (int i = t; i < 16 * IN_F / 4; i += 256) hs4[i] = h4[i];
    __syncthreads();

    float acc[16];
#pragma unroll
    for (int r = 0; r < 16; ++r) acc[r] = 0.f;
    for (int k = 0; k < IN_F; ++k) {
        float wk = fcw[k * HO + t];
#pragma unroll
        for (int r = 0; r < 16; ++r) acc[r] = fmaf(hs[r][k], wk, acc[r]);
    }
#pragma unroll
    for (int r = 0; r < 16; ++r)
        feat[(size_t)(row0 + r) * HO + t] = (bf16)acc[r];

    // el[n,h] = sum_d feat[n,h*64+d]*al[h,d]  (wave = head, lane = d), fp32
    const int hh = t >> 6, c = t & 63;
    const float alc = al[hh * D_HEAD + c];
    const float arc = ar[hh * D_HEAD + c];
#pragma unroll
    for (int r = 0; r < 16; ++r) {
        float vl = acc[r] * alc, vr = acc[r] * arc;
#pragma unroll
        for (int off = 32; off; off >>= 1) {
            vl += __shfl_down(vl, off, 64);
            vr += __shfl_down(vr, off, 64);
        }
        if (c == 0) {
            el[(row0 + r) * N_HEADS + hh] = vl;
            er[(row0 + r) * N_HEADS + hh] = vr;
        }
    }
}

// ---- CSR build: count+rank (one atomic pass), scan, scatter (no atomics) ---
__global__ void k_count(const int* __restrict__ edges, int* __restrict__ deg,
                        int* __restrict__ rank) {
    int g = blockIdx.x * blockDim.x + threadIdx.x;
    if (g >= N_PATHS * N_EDGES) return;
    int p = g / N_EDGES, e = g - p * N_EDGES;
    const int d = edges[(size_t)p * 2 * N_EDGES + N_EDGES + e];
    rank[g] = atomicAdd(&deg[p * N_NODES + d], 1);
}

__global__ __launch_bounds__(1024) void k_scan(const int* __restrict__ deg,
                                               int* __restrict__ rowptr) {
    __shared__ int part[1024];
    const int p = blockIdx.x;
    const int* dg = deg + p * N_NODES;
    int* rp = rowptr + p * (N_NODES + 1);

    const int tid = threadIdx.x;
    const int CH = (N_NODES + 1023) / 1024;       // 49
    const int start = tid * CH;
    int s = 0;
    for (int i = 0; i < CH; ++i) { int idx = start + i; if (idx < N_NODES) s += dg[idx]; }
    part[tid] = s;
    __syncthreads();
    for (int off = 1; off < 1024; off <<= 1) {
        int v = (tid >= off) ? part[tid - off] : 0;
        __syncthreads();
        part[tid] += v;
        __syncthreads();
    }
    int excl = (tid == 0) ? 0 : part[tid - 1];
    for (int i = 0; i < CH; ++i) {
        int idx = start + i;
        if (idx < N_NODES) { rp[idx] = excl; excl += dg[idx]; }
    }
    if (tid == 1023) rp[N_NODES] = N_EDGES;
}

__global__ void k_scatter(const int* __restrict__ edges, const int* __restrict__ rank,
                          const int* __restrict__ rowptr, int* __restrict__ csr_src) {
    int g = blockIdx.x * blockDim.x + threadIdx.x;
    if (g >= N_PATHS * N_EDGES) return;
    int p = g / N_EDGES, e = g - p * N_EDGES;
    const int s = edges[(size_t)p * 2 * N_EDGES + e];
    const int d = edges[(size_t)p * 2 * N_EDGES + N_EDGES + e];
    const int pos = rowptr[p * (N_NODES + 1) + d] + rank[g];
    csr_src[(size_t)p * N_EDGES + pos] = s;       // fire-and-forget store
}

// ---- gather: one wave per node, no barriers, no atomics --------------------
__global__ __launch_bounds__(256) void k_gather(const int* __restrict__ csr_src,
                                                const int* __restrict__ rowptr,
                                                const float4* __restrict__ el4,
                                                const float4* __restrict__ er4,
                                                const bf16* __restrict__ feat,
                                                float* __restrict__ z /* + p*HO */) {
    __shared__ float exbuf[4][64 * N_HEADS];       // per-wave ex staging
    const int wid = threadIdx.x >> 6, l = threadIdx.x & 63;
    const int n = blockIdx.x * 4 + wid;            // 50000 % 4 == 0

    const int b0 = rowptr[n], b1 = rowptr[n + 1];
    const float4 er_n = er4[n];
    float* exw = exbuf[wid];

    float4 acc = {0.f, 0.f, 0.f, 0.f};
    float4 den = {0.f, 0.f, 0.f, 0.f};

    for (int base = b0; base < b1; base += 64) {
        const int cnt = min(64, b1 - base);
        int sv = 0;
        if (l < cnt) {
            sv = csr_src[base + l];                // direct src id
            float4 e = el4[sv];
            float vx = e.x + er_n.x, vy = e.y + er_n.y,
                  vz = e.z + er_n.z, vw = e.w + er_n.w;
            vx = (vx >= 0.f) ? vx : 0.2f * vx;
            vy = (vy >= 0.f) ? vy : 0.2f * vy;
            vz = (vz >= 0.f) ? vz : 0.2f * vz;
            vw = (vw >= 0.f) ? vw : 0.2f * vw;
            float4 ex = make_float4(__expf(vx), __expf(vy), __expf(vz), __expf(vw));
            *(float4*)&exw[l * 4] = ex;
            den.x += ex.x; den.y += ex.y; den.z += ex.z; den.w += ex.w;
        }
        // accumulate: lane l owns cols 4l..4l+3 (head l>>4); wave reads 512B/edge
        const int hh = l >> 4;
        for (int i = 0; i < cnt; ++i) {
            int sV  = __shfl(sv, i, 64);
            float a = exw[i * 4 + hh];             // 4-addr broadcast
            bf16x4 f = *(const bf16x4*)(feat + (size_t)sV * HO + l * 4);
            acc.x = fmaf((float)f[0], a, acc.x);
            acc.y = fmaf((float)f[1], a, acc.y);
            acc.z = fmaf((float)f[2], a, acc.z);
            acc.w = fmaf((float)f[3], a, acc.w);
        }
    }

    // denominator: butterfly over full wave (per-lane partials -> total)
#pragma unroll
    for (int off = 32; off; off >>= 1) {
        den.x += __shfl_xor(den.x, off, 64);
        den.y += __shfl_xor(den.y, off, 64);
        den.z += __shfl_xor(den.z, off, 64);
        den.w += __shfl_xor(den.w, off, 64);
    }
    const int hh = l >> 4;
    float d = (hh == 0) ? den.x : (hh == 1) ? den.y : (hh == 2) ? den.z : den.w;
    float inv = (d > 0.f) ? 1.f / d : 0.f;
    float4 r;
    r.x = acc.x * inv; r.y = acc.y * inv; r.z = acc.z * inv; r.w = acc.w * inv;
    r.x = (r.x > 0.f) ? r.x : expm1f(r.x);
    r.y = (r.y > 0.f) ? r.y : expm1f(r.y);
    r.z = (r.z > 0.f) ? r.z : expm1f(r.z);
    r.w = (r.w > 0.f) ? r.w : expm1f(r.w);
    *(float4*)&z[(size_t)n * (N_PATHS * HO) + l * 4] = r;
}

// ---- fused semantic attention + output: MFMA logits, fp32 combine ----------
__global__ __launch_bounds__(256) void k_semout(const float* __restrict__ z,
                                                const float* __restrict__ w1,
                                                const float* __restrict__ b1,
                                                const float* __restrict__ w2,
                                                float* __restrict__ out) {
    __shared__ float zs[48 * 260];                 // 49,920 B, 2-way conflicts only
    __shared__ float psem[4][48];
    __shared__ float betas[16][4];

    const int t = threadIdx.x, w = t >> 6, l = t & 63;
    const int lo = l & 15, hi = l >> 4;
    const int n0 = blockIdx.x * 16;
    const float* zg = z + (size_t)n0 * (N_PATHS * HO);

    // B-frag preload: wave w covers col-tiles 2w,2w+1
    bf16x8 bfr[2][8];
#pragma unroll
    for (int ct = 0; ct < 2; ++ct) {
        const int j = (2 * w + ct) * 16 + lo;
#pragma unroll
        for (int s = 0; s < 8; ++s) {
            const int k0 = s * 32 + hi * 8;
            bf16x8 b;
#pragma unroll
            for (int i = 0; i < 8; ++i) b[i] = (bf16)w1[(k0 + i) * HID + j];
            bfr[ct][s] = b;
        }
    }

    // stage 48 rows x 256 cols (contiguous in z) into padded LDS
    for (int i = t; i < 48 * 64; i += 256) {
        float4 v = ((const float4*)zg)[i];
        int r = i >> 6, c = (i & 63) << 2;
        *(float4*)&zs[r * 260 + c] = v;
    }
    __syncthreads();

    f32x4 acc[2][3];
#pragma unroll
    for (int ct = 0; ct < 2; ++ct)
#pragma unroll
        for (int m = 0; m < 3; ++m) { f32x4 zz = {0.f,0.f,0.f,0.f}; acc[ct][m] = zz; }

    for (int s = 0; s < 8; ++s) {
#pragma unroll
        for (int m = 0; m < 3; ++m) {
            const float* ap = &zs[(m * 16 + lo) * 260 + s * 32 + hi * 8];
            float4 f0 = *(const float4*)ap;
            float4 f1 = *(const float4*)(ap + 4);
            bf16x8 a;
            a[0]=(bf16)f0.x; a[1]=(bf16)f0.y; a[2]=(bf16)f0.z; a[3]=(bf16)f0.w;
            a[4]=(bf16)f1.x; a[5]=(bf16)f1.y; a[6]=(bf16)f1.z; a[7]=(bf16)f1.w;
            acc[0][m] = __builtin_amdgcn_mfma_f32_16x16x32_bf16(a, bfr[0][s], acc[0][m], 0, 0, 0);
            acc[1][m] = __builtin_amdgcn_mfma_f32_16x16x32_bf16(a, bfr[1][s], acc[1][m], 0, 0, 0);
        }
    }

    // epilogue: tanh(acc + b1)*w2, reduce over cols (lane bits 0..3)
    const int j0 = (2 * w + 0) * 16 + lo;
    const int j1 = (2 * w + 1) * 16 + lo;
    const float b1_0 = b1[j0], w2_0 = w2[j0];
    const float b1_1 = b1[j1], w2_1 = w2[j1];
#pragma unroll
    for (int m = 0; m < 3; ++m) {
#pragma unroll
        for (int r = 0; r < 4; ++r) {
            float tt = tanhf(acc[0][m][r] + b1_0) * w2_0
                     + tanhf(acc[1][m][r] + b1_1) * w2_1;
            tt += __shfl_xor(tt, 1, 64);
            tt += __shfl_xor(tt, 2, 64);
            tt += __shfl_xor(tt, 4, 64);
            tt += __shfl_xor(tt, 8, 64);
            if (lo == 0) psem[w][m * 16 + hi * 4 + r] = tt;
        }
    }
    __syncthreads();
    if (t < 48) psem[0][t] = psem[0][t] + psem[1][t] + psem[2][t] + psem[3][t];
    __syncthreads();
    if (t < 16) {
        float a0 = psem[0][3 * t], a1 = psem[0][3 * t + 1], a2 = psem[0][3 * t + 2];
        float mx = fmaxf(a0, fmaxf(a1, a2));
        float e0 = __expf(a0 - mx), e1 = __expf(a1 - mx), e2 = __expf(a2 - mx);
        float is = 1.f / (e0 + e1 + e2);
        betas[t][0] = e0 * is; betas[t][1] = e1 * is; betas[t][2] = e2 * is;
    }
    __syncthreads();
    // combine from fp32 LDS copy
    for (int i = 0; i < 16; ++i) {
        float bb0 = betas[i][0], bb1 = betas[i][1], bb2 = betas[i][2];
        float o = bb0 * zs[(3 * i + 0) * 260 + t]
                + bb1 * zs[(3 * i + 1) * 260 + t]
                + bb2 * zs[(3 * i + 2) * 260 + t];
        out[(size_t)(n0 + i) * HO + t] = o;
    }
}

// ---------------------------------------------------------------------------
static inline size_t align256(size_t x) { return (x + 255) & ~(size_t)255; }

extern "C" void kernel_launch(void* const* d_in, const int* in_sizes, int n_in,
                              void* d_out, int out_size, void* d_ws, size_t ws_size,
                              hipStream_t stream) {
    const float* h     = (const float*)d_in[0];
    const int*   edges = (const int*)d_in[1];     // [P,2,E]
    const float* fc_w  = (const float*)d_in[2];   // [P,128,256]
    const float* al    = (const float*)d_in[3];   // [P,4,64]
    const float* ar    = (const float*)d_in[4];
    const float* w1    = (const float*)d_in[5];   // [256,128]
    const float* b1    = (const float*)d_in[6];   // [128]
    const float* w2    = (const float*)d_in[7];   // [128]
    float* out = (float*)d_out;

    char* base = (char*)d_ws;
    size_t off = 0;
    auto carve = [&](size_t bytes) -> char* {
        char* p = base + off; off = align256(off + bytes); return p;
    };
    bf16*  feat    = (bf16*)carve((size_t)N_NODES * HO * 2);             // 25.6 MB
    float* z       = (float*)carve((size_t)N_NODES * N_PATHS * HO * 4);  // 153.6 MB
    float* el      = (float*)carve((size_t)N_NODES * N_HEADS * 4);
    float* er      = (float*)carve((size_t)N_NODES * N_HEADS * 4);
    int*   deg     = (int*)carve((size_t)N_PATHS * N_NODES * 4);
    int*   rowptr  = (int*)carve((size_t)N_PATHS * (N_NODES + 1) * 4);
    int*   rank    = (int*)carve((size_t)N_PATHS * N_EDGES * 4);         // 9.6 MB
    int*   csr_src = (int*)carve((size_t)N_PATHS * N_EDGES * 4);         // 9.6 MB
    (void)ws_size; (void)in_sizes; (void)n_in; (void)out_size;

    // batched CSR build: ONE atomic pass, then scan, then atomic-free scatter
    hipMemsetAsync(deg, 0, (size_t)N_PATHS * N_NODES * 4, stream);
    k_count<<<(N_PATHS * N_EDGES + 255) / 256, 256, 0, stream>>>(edges, deg, rank);
    k_scan<<<N_PATHS, 1024, 0, stream>>>(deg, rowptr);
    k_scatter<<<(N_PATHS * N_EDGES + 255) / 256, 256, 0, stream>>>(edges, rank, rowptr, csr_src);

    for (int p = 0; p < N_PATHS; ++p) {
        k_feat<<<N_NODES / 16, 256, 0, stream>>>(
            h, fc_w + (size_t)p * IN_F * HO,
            al + p * N_HEADS * D_HEAD, ar + p * N_HEADS * D_HEAD, feat, el, er);
        k_gather<<<N_NODES / 4, 256, 0, stream>>>(
            csr_src + (size_t)p * N_EDGES, rowptr + p * (N_NODES + 1),
            (const float4*)el, (const float4*)er, feat, z + p * HO);
    }
    k_semout<<<N_NODES / 16, 256, 0, stream>>>(z, w1, b1, w2, out);
}

// Round 5
// 631.985 us; speedup vs baseline: 3.2771x; 1.3101x over previous
//
#include <hip/hip_runtime.h>
#include <hip/hip_bf16.h>

#define N_NODES 50000
#define N_EDGES 800000
#define N_PATHS 3
#define IN_F    128
#define HO      256   // H*OUT
#define N_HEADS 4
#define D_HEAD  64
#define HID     128

#define FEAT_RB     782                 // ceil(50000/64) row-blocks
#define FEAT_BLOCKS (FEAT_RB * 2)       // x2 col-halves, per path
#define SCAT_BLOCKS ((N_PATHS * N_EDGES) / 256)   // 9375
#define FEAT_ELEMS  ((size_t)N_NODES * HO)

typedef __bf16 bf16;
typedef __bf16 bf16x4 __attribute__((ext_vector_type(4)));
typedef __bf16 bf16x8 __attribute__((ext_vector_type(8)));
typedef float  f32x4  __attribute__((ext_vector_type(4)));
typedef unsigned short u16;

// ---- prep: fcwT[p][col][k] bf16 from fc_w[p][k][col] f32 -------------------
__global__ __launch_bounds__(256) void k_prep(const float* __restrict__ fc_w,
                                              bf16* __restrict__ fcwT) {
    int g = blockIdx.x * 256 + threadIdx.x;
    if (g >= N_PATHS * IN_F * HO) return;
    int p = g >> 15, r = g & 32767;
    int col = r & 255, k = r >> 8;                 // coalesced read along col
    fcwT[(size_t)p * 32768 + col * IN_F + k] = (bf16)fc_w[(size_t)p * 32768 + k * HO + col];
}

// ---- count: one atomic pass, emits per-edge rank (u16) ---------------------
__global__ void k_count(const int* __restrict__ edges, int* __restrict__ deg,
                        u16* __restrict__ rank) {
    int g = blockIdx.x * blockDim.x + threadIdx.x;
    if (g >= N_PATHS * N_EDGES) return;
    int p = g / N_EDGES, e = g - p * N_EDGES;
    const int d = edges[(size_t)p * 2 * N_EDGES + N_EDGES + e];
    rank[g] = (u16)atomicAdd(&deg[p * N_NODES + d], 1);
}

__global__ __launch_bounds__(1024) void k_scan(const int* __restrict__ deg,
                                               int* __restrict__ rowptr) {
    __shared__ int part[1024];
    const int p = blockIdx.x;
    const int* dg = deg + p * N_NODES;
    int* rp = rowptr + p * (N_NODES + 1);

    const int tid = threadIdx.x;
    const int CH = (N_NODES + 1023) / 1024;       // 49
    const int start = tid * CH;
    int s = 0;
    for (int i = 0; i < CH; ++i) { int idx = start + i; if (idx < N_NODES) s += dg[idx]; }
    part[tid] = s;
    __syncthreads();
    for (int off = 1; off < 1024; off <<= 1) {
        int v = (tid >= off) ? part[tid - off] : 0;
        __syncthreads();
        part[tid] += v;
        __syncthreads();
    }
    int excl = (tid == 0) ? 0 : part[tid - 1];
    for (int i = 0; i < CH; ++i) {
        int idx = start + i;
        if (idx < N_NODES) { rp[idx] = excl; excl += dg[idx]; }
    }
    if (tid == 1023) rp[N_NODES] = N_EDGES;
}

// ---- fused: MFMA feat (all 3 paths) CONCURRENT with CSR scatter ------------
__device__ __forceinline__ void feat_role(int r, const float* __restrict__ h,
                                          const bf16* __restrict__ fcwT,
                                          const float* __restrict__ al,
                                          const float* __restrict__ ar,
                                          bf16* __restrict__ featAll,
                                          float* __restrict__ elAll,
                                          float* __restrict__ erAll) {
    const int p  = r / FEAT_BLOCKS;
    const int q  = r - p * FEAT_BLOCKS;
    const int rb = q >> 1;                         // 64-row block
    const int ch = q & 1;                          // 128-col half
    const int t = threadIdx.x, w = t >> 6, l = t & 63, lo = l & 15, hi = l >> 4;
    const int arow = rb * 64 + w * 16 + lo;        // A-frag row
    const bf16* W = fcwT + (size_t)p * 32768 + (size_t)ch * 128 * IN_F;
    bf16* feat = featAll + (size_t)p * FEAT_ELEMS;

    // A frags: h[arow][k], k = ks*32 + hi*8 + i  (fp32 -> bf16)
    bf16x8 afr[4];
    if (arow < N_NODES) {
        const float* hp = h + (size_t)arow * IN_F;
#pragma unroll
        for (int ks = 0; ks < 4; ++ks) {
            float4 f0 = *(const float4*)(hp + ks * 32 + hi * 8);
            float4 f1 = *(const float4*)(hp + ks * 32 + hi * 8 + 4);
            bf16x8 a;
            a[0]=(bf16)f0.x; a[1]=(bf16)f0.y; a[2]=(bf16)f0.z; a[3]=(bf16)f0.w;
            a[4]=(bf16)f1.x; a[5]=(bf16)f1.y; a[6]=(bf16)f1.z; a[7]=(bf16)f1.w;
            afr[ks] = a;
        }
    } else {
#pragma unroll
        for (int ks = 0; ks < 4; ++ks) { bf16x8 a = {}; afr[ks] = a; }
    }

    f32x4 acc[8];
#pragma unroll
    for (int c = 0; c < 8; ++c) { f32x4 zz = {0.f,0.f,0.f,0.f}; acc[c] = zz; }
#pragma unroll
    for (int ctl = 0; ctl < 8; ++ctl) {
        const bf16* wp = W + (size_t)(ctl * 16 + lo) * IN_F + hi * 8;
        f32x4 a = acc[ctl];
#pragma unroll
        for (int ks = 0; ks < 4; ++ks)
            a = __builtin_amdgcn_mfma_f32_16x16x32_bf16(afr[ks], *(const bf16x8*)(wp + ks * 32), a, 0, 0, 0);
        acc[ctl] = a;
    }

    // epilogue: feat store + fused el/er (C: col=lane&15, row=(lane>>4)*4+reg)
    const float* alp = al + p * HO;
    const float* arp = ar + p * HO;
    const int crow = rb * 64 + w * 16 + hi * 4;
    float elP[2][4] = {{0}}, erP[2][4] = {{0}};
#pragma unroll
    for (int ctl = 0; ctl < 8; ++ctl) {
        const int gcol = ch * 128 + ctl * 16 + lo;
        const float av = alp[gcol], bv = arp[gcol];
        const int hl = ctl >> 2;                   // local head (0/1)
#pragma unroll
        for (int rr = 0; rr < 4; ++rr) {
            float v = acc[ctl][rr];
            elP[hl][rr] = fmaf(v, av, elP[hl][rr]);
            erP[hl][rr] = fmaf(v, bv, erP[hl][rr]);
            if (crow + rr < N_NODES)
                feat[(size_t)(crow + rr) * HO + gcol] = (bf16)v;
        }
    }
#pragma unroll
    for (int hl = 0; hl < 2; ++hl)
#pragma unroll
        for (int rr = 0; rr < 4; ++rr) {
            float v = elP[hl][rr], u = erP[hl][rr];
#pragma unroll
            for (int m = 1; m <= 8; m <<= 1) {
                v += __shfl_xor(v, m, 64);
                u += __shfl_xor(u, m, 64);
            }
            elP[hl][rr] = v; erP[hl][rr] = u;
        }
    if (lo == 0) {
        float* elA = elAll + (size_t)p * N_NODES * 4;
        float* erA = erAll + (size_t)p * N_NODES * 4;
#pragma unroll
        for (int rr = 0; rr < 4; ++rr) {
            if (crow + rr < N_NODES) {
                *(float2*)&elA[(crow + rr) * 4 + ch * 2] = make_float2(elP[0][rr], elP[1][rr]);
                *(float2*)&erA[(crow + rr) * 4 + ch * 2] = make_float2(erP[0][rr], erP[1][rr]);
            }
        }
    }
}

__device__ __forceinline__ void scatter_role(int b, const int* __restrict__ edges,
                                             const u16* __restrict__ rank,
                                             const int* __restrict__ rowptr,
                                             u16* __restrict__ csr) {
    int g = b * 256 + threadIdx.x;
    if (g >= N_PATHS * N_EDGES) return;
    int p = g / N_EDGES, e = g - p * N_EDGES;
    const int s = edges[(size_t)p * 2 * N_EDGES + e];
    const int d = edges[(size_t)p * 2 * N_EDGES + N_EDGES + e];
    const int pos = rowptr[p * (N_NODES + 1) + d] + rank[g];
    csr[(size_t)p * N_EDGES + pos] = (u16)s;       // fire-and-forget
}

__global__ __launch_bounds__(256, 4) void k_sf(const int* __restrict__ edges,
                                               const u16* __restrict__ rank,
                                               const int* __restrict__ rowptr,
                                               u16* __restrict__ csr,
                                               const float* __restrict__ h,
                                               const bf16* __restrict__ fcwT,
                                               const float* __restrict__ al,
                                               const float* __restrict__ ar,
                                               bf16* __restrict__ featAll,
                                               float* __restrict__ elAll,
                                               float* __restrict__ erAll) {
    const int bid = blockIdx.x;
    if (bid < N_PATHS * FEAT_BLOCKS)
        feat_role(bid, h, fcwT, al, ar, featAll, elAll, erAll);
    else
        scatter_role(bid - N_PATHS * FEAT_BLOCKS, edges, rank, rowptr, csr);
}

// ---- gather, all 3 paths in one grid: wave-per-node ------------------------
__global__ __launch_bounds__(256) void k_gather3(const u16* __restrict__ csrAll,
                                                 const int* __restrict__ rowptrAll,
                                                 const float4* __restrict__ elAll,
                                                 const float4* __restrict__ erAll,
                                                 const bf16* __restrict__ featAll,
                                                 float* __restrict__ z) {
    __shared__ float exbuf[4][64 * N_HEADS];
    const int pb = blockIdx.x;
    const int p  = pb / (N_NODES / 4);
    const int nb = pb - p * (N_NODES / 4);
    const u16*    csr    = csrAll + (size_t)p * N_EDGES;
    const int*    rowptr = rowptrAll + p * (N_NODES + 1);
    const float4* el4    = elAll + (size_t)p * N_NODES;
    const float4* er4    = erAll + (size_t)p * N_NODES;
    const bf16*   feat   = featAll + (size_t)p * FEAT_ELEMS;

    const int wid = threadIdx.x >> 6, l = threadIdx.x & 63;
    const int n = nb * 4 + wid;

    const int b0 = rowptr[n], b1 = rowptr[n + 1];
    const float4 er_n = er4[n];
    float* exw = exbuf[wid];

    float4 acc = {0.f, 0.f, 0.f, 0.f};
    float4 den = {0.f, 0.f, 0.f, 0.f};

    for (int base = b0; base < b1; base += 64) {
        const int cnt = min(64, b1 - base);
        int sv = 0;
        if (l < cnt) {
            sv = csr[base + l];
            float4 e = el4[sv];
            float vx = e.x + er_n.x, vy = e.y + er_n.y,
                  vz = e.z + er_n.z, vw = e.w + er_n.w;
            vx = (vx >= 0.f) ? vx : 0.2f * vx;
            vy = (vy >= 0.f) ? vy : 0.2f * vy;
            vz = (vz >= 0.f) ? vz : 0.2f * vz;
            vw = (vw >= 0.f) ? vw : 0.2f * vw;
            float4 ex = make_float4(__expf(vx), __expf(vy), __expf(vz), __expf(vw));
            *(float4*)&exw[l * 4] = ex;
            den.x += ex.x; den.y += ex.y; den.z += ex.z; den.w += ex.w;
        }
        const int hh = l >> 4;
        for (int i = 0; i < cnt; ++i) {
            int sV  = __shfl(sv, i, 64);
            float a = exw[i * 4 + hh];
            bf16x4 f = *(const bf16x4*)(feat + (size_t)sV * HO + l * 4);
            acc.x = fmaf((float)f[0], a, acc.x);
            acc.y = fmaf((float)f[1], a, acc.y);
            acc.z = fmaf((float)f[2], a, acc.z);
            acc.w = fmaf((float)f[3], a, acc.w);
        }
    }

#pragma unroll
    for (int off = 32; off; off >>= 1) {
        den.x += __shfl_xor(den.x, off, 64);
        den.y += __shfl_xor(den.y, off, 64);
        den.z += __shfl_xor(den.z, off, 64);
        den.w += __shfl_xor(den.w, off, 64);
    }
    const int hh = l >> 4;
    float d = (hh == 0) ? den.x : (hh == 1) ? den.y : (hh == 2) ? den.z : den.w;
    float inv = (d > 0.f) ? 1.f / d : 0.f;
    float4 r;
    r.x = acc.x * inv; r.y = acc.y * inv; r.z = acc.z * inv; r.w = acc.w * inv;
    r.x = (r.x > 0.f) ? r.x : expm1f(r.x);
    r.y = (r.y > 0.f) ? r.y : expm1f(r.y);
    r.z = (r.z > 0.f) ? r.z : expm1f(r.z);
    r.w = (r.w > 0.f) ? r.w : expm1f(r.w);
    *(float4*)&z[(size_t)n * (N_PATHS * HO) + p * HO + l * 4] = r;
}

// ---- fused semantic attention + output: MFMA logits, fp32 combine ----------
__global__ __launch_bounds__(256) void k_semout(const float* __restrict__ z,
                                                const float* __restrict__ w1,
                                                const float* __restrict__ b1,
                                                const float* __restrict__ w2,
                                                float* __restrict__ out) {
    __shared__ float zs[48 * 260];
    __shared__ float psem[4][48];
    __shared__ float betas[16][4];

    const int t = threadIdx.x, w = t >> 6, l = t & 63;
    const int lo = l & 15, hi = l >> 4;
    const int n0 = blockIdx.x * 16;
    const float* zg = z + (size_t)n0 * (N_PATHS * HO);

    bf16x8 bfr[2][8];
#pragma unroll
    for (int ct = 0; ct < 2; ++ct) {
        const int j = (2 * w + ct) * 16 + lo;
#pragma unroll
        for (int s = 0; s < 8; ++s) {
            const int k0 = s * 32 + hi * 8;
            bf16x8 b;
#pragma unroll
            for (int i = 0; i < 8; ++i) b[i] = (bf16)w1[(k0 + i) * HID + j];
            bfr[ct][s] = b;
        }
    }

    for (int i = t; i < 48 * 64; i += 256) {
        float4 v = ((const float4*)zg)[i];
        int r = i >> 6, c = (i & 63) << 2;
        *(float4*)&zs[r * 260 + c] = v;
    }
    __syncthreads();

    f32x4 acc[2][3];
#pragma unroll
    for (int ct = 0; ct < 2; ++ct)
#pragma unroll
        for (int m = 0; m < 3; ++m) { f32x4 zz = {0.f,0.f,0.f,0.f}; acc[ct][m] = zz; }

    for (int s = 0; s < 8; ++s) {
#pragma unroll
        for (int m = 0; m < 3; ++m) {
            const float* ap = &zs[(m * 16 + lo) * 260 + s * 32 + hi * 8];
            float4 f0 = *(const float4*)ap;
            float4 f1 = *(const float4*)(ap + 4);
            bf16x8 a;
            a[0]=(bf16)f0.x; a[1]=(bf16)f0.y; a[2]=(bf16)f0.z; a[3]=(bf16)f0.w;
            a[4]=(bf16)f1.x; a[5]=(bf16)f1.y; a[6]=(bf16)f1.z; a[7]=(bf16)f1.w;
            acc[0][m] = __builtin_amdgcn_mfma_f32_16x16x32_bf16(a, bfr[0][s], acc[0][m], 0, 0, 0);
            acc[1][m] = __builtin_amdgcn_mfma_f32_16x16x32_bf16(a, bfr[1][s], acc[1][m], 0, 0, 0);
        }
    }

    const int j0 = (2 * w + 0) * 16 + lo;
    const int j1 = (2 * w + 1) * 16 + lo;
    const float b1_0 = b1[j0], w2_0 = w2[j0];
    const float b1_1 = b1[j1], w2_1 = w2[j1];
#pragma unroll
    for (int m = 0; m < 3; ++m) {
#pragma unroll
        for (int r = 0; r < 4; ++r) {
            float tt = tanhf(acc[0][m][r] + b1_0) * w2_0
                     + tanhf(acc[1][m][r] + b1_1) * w2_1;
            tt += __shfl_xor(tt, 1, 64);
            tt += __shfl_xor(tt, 2, 64);
            tt += __shfl_xor(tt, 4, 64);
            tt += __shfl_xor(tt, 8, 64);
            if (lo == 0) psem[w][m * 16 + hi * 4 + r] = tt;
        }
    }
    __syncthreads();
    if (t < 48) psem[0][t] = psem[0][t] + psem[1][t] + psem[2][t] + psem[3][t];
    __syncthreads();
    if (t < 16) {
        float a0 = psem[0][3 * t], a1 = psem[0][3 * t + 1], a2 = psem[0][3 * t + 2];
        float mx = fmaxf(a0, fmaxf(a1, a2));
        float e0 = __expf(a0 - mx), e1 = __expf(a1 - mx), e2 = __expf(a2 - mx);
        float is = 1.f / (e0 + e1 + e2);
        betas[t][0] = e0 * is; betas[t][1] = e1 * is; betas[t][2] = e2 * is;
    }
    __syncthreads();
    for (int i = 0; i < 16; ++i) {
        float bb0 = betas[i][0], bb1 = betas[i][1], bb2 = betas[i][2];
        float o = bb0 * zs[(3 * i + 0) * 260 + t]
                + bb1 * zs[(3 * i + 1) * 260 + t]
                + bb2 * zs[(3 * i + 2) * 260 + t];
        out[(size_t)(n0 + i) * HO + t] = o;
    }
}

// ---------------------------------------------------------------------------
static inline size_t align256(size_t x) { return (x + 255) & ~(size_t)255; }

extern "C" void kernel_launch(void* const* d_in, const int* in_sizes, int n_in,
                              void* d_out, int out_size, void* d_ws, size_t ws_size,
                              hipStream_t stream) {
    const float* h     = (const float*)d_in[0];
    const int*   edges = (const int*)d_in[1];     // [P,2,E]
    const float* fc_w  = (const float*)d_in[2];   // [P,128,256]
    const float* al    = (const float*)d_in[3];   // [P,4,64]
    const float* ar    = (const float*)d_in[4];
    const float* w1    = (const float*)d_in[5];   // [256,128]
    const float* b1    = (const float*)d_in[6];   // [128]
    const float* w2    = (const float*)d_in[7];   // [128]
    float* out = (float*)d_out;

    char* base = (char*)d_ws;
    size_t off = 0;
    auto carve = [&](size_t bytes) -> char* {
        char* p = base + off; off = align256(off + bytes); return p;
    };
    float* z      = (float*)carve((size_t)N_NODES * N_PATHS * HO * 4);   // 153.6 MB
    bf16*  feat   = (bf16*)carve((size_t)N_PATHS * FEAT_ELEMS * 2);      // 76.8 MB
    bf16*  fcwT   = (bf16*)carve((size_t)N_PATHS * IN_F * HO * 2);       // 192 KB
    float* el     = (float*)carve((size_t)N_PATHS * N_NODES * 4 * 4);    // 2.4 MB
    float* er     = (float*)carve((size_t)N_PATHS * N_NODES * 4 * 4);    // 2.4 MB
    int*   deg    = (int*)carve((size_t)N_PATHS * N_NODES * 4);
    int*   rowptr = (int*)carve((size_t)N_PATHS * (N_NODES + 1) * 4);
    u16*   rank   = (u16*)carve((size_t)N_PATHS * N_EDGES * 2);          // 4.8 MB
    u16*   csr    = (u16*)carve((size_t)N_PATHS * N_EDGES * 2);          // 4.8 MB
    (void)ws_size; (void)in_sizes; (void)n_in; (void)out_size;

    hipMemsetAsync(deg, 0, (size_t)N_PATHS * N_NODES * 4, stream);
    k_prep<<<(N_PATHS * IN_F * HO) / 256, 256, 0, stream>>>(fc_w, fcwT);
    k_count<<<SCAT_BLOCKS, 256, 0, stream>>>(edges, deg, rank);
    k_scan<<<N_PATHS, 1024, 0, stream>>>(deg, rowptr);
    // scatter (store-bound) overlapped with all 3 MFMA feat GEMMs (compute-bound)
    k_sf<<<N_PATHS * FEAT_BLOCKS + SCAT_BLOCKS, 256, 0, stream>>>(
        edges, rank, rowptr, csr, h, fcwT, al, ar, feat, el, er);
    k_gather3<<<N_PATHS * (N_NODES / 4), 256, 0, stream>>>(
        csr, rowptr, (const float4*)el, (const float4*)er, feat, z);
    k_semout<<<N_NODES / 16, 256, 0, stream>>>(z, w1, b1, w2, out);
}

// Round 6
// 558.300 us; speedup vs baseline: 3.7096x; 1.1320x over previous
//
#include <hip/hip_runtime.h>
#include <hip/hip_bf16.h>
#include <hip/hip_fp16.h>

#define N_NODES 50000
#define N_EDGES 800000
#define N_PATHS 3
#define IN_F    128
#define HO      256   // H*OUT
#define N_HEADS 4
#define HID     128

#define FEAT_RB       782     // ceil(50000/64) row-blocks (fat: all 6 tiles each)
#define CNT_BLOCKS    2344    // ceil(2.4M edges / (256 thr * 4 edges))
#define SCAT_BLOCKS   2344
#define PREP_T_BLOCKS 384     // 3*128*256 / 256
#define PREP_Z_BLOCKS 147     // 37500 int4 / 256
#define FEAT_ELEMS    ((size_t)N_NODES * HO)

typedef __bf16 bf16;
typedef __bf16 bf16x8 __attribute__((ext_vector_type(8)));
typedef float  f32x4  __attribute__((ext_vector_type(4)));
typedef unsigned short u16;

// ---- prep: fcwT[p][col][k] bf16 transpose  +  deg zero-fill ----------------
__global__ __launch_bounds__(256) void k_prep(const float* __restrict__ fc_w,
                                              bf16* __restrict__ fcwT,
                                              int* __restrict__ deg) {
    const int b = blockIdx.x;
    if (b < PREP_T_BLOCKS) {
        int g = b * 256 + threadIdx.x;                 // < 98304
        int p = g >> 15, r = g & 32767;
        int col = r & 255, k = r >> 8;
        fcwT[(size_t)p * 32768 + col * IN_F + k] = (bf16)fc_w[(size_t)p * 32768 + k * HO + col];
    } else {
        int g = (b - PREP_T_BLOCKS) * 256 + threadIdx.x;
        if (g < (N_PATHS * N_NODES) / 4) {             // 150000 % 4 == 0
            int4 zz = {0, 0, 0, 0};
            ((int4*)deg)[g] = zz;
        }
    }
}

// ---- count role: 4 edges/thread, 4 independent atomic chains ---------------
__device__ __forceinline__ void count_role(int b, const int* __restrict__ edges,
                                           int* __restrict__ deg, u16* __restrict__ rank) {
    int gt = b * 256 + threadIdx.x;
    if (gt >= (N_PATHS * N_EDGES) / 4) return;
    int base = gt * 4;                                 // quad never crosses a path (800000%4==0)
    int p = base / N_EDGES, e = base - p * N_EDGES;
    const int* dstp = edges + (size_t)p * 2 * N_EDGES + N_EDGES;
    int4 d4 = *(const int4*)(dstp + e);
    int* dg = deg + p * N_NODES;
    u16 r0 = (u16)atomicAdd(&dg[d4.x], 1);
    u16 r1 = (u16)atomicAdd(&dg[d4.y], 1);
    u16 r2 = (u16)atomicAdd(&dg[d4.z], 1);
    u16 r3 = (u16)atomicAdd(&dg[d4.w], 1);
    ushort4 rr = {r0, r1, r2, r3};
    *(ushort4*)(rank + base) = rr;
}

// ---- fat feat role: one 64-row block does all 3 paths x 2 col-halves -------
__device__ __forceinline__ void feat_role(int rb, const float* __restrict__ h,
                                          const bf16* __restrict__ fcwT,
                                          const float* __restrict__ al,
                                          const float* __restrict__ ar,
                                          __half* __restrict__ featAll,
                                          float* __restrict__ elAll,
                                          float* __restrict__ erAll) {
    const int t = threadIdx.x, w = t >> 6, l = t & 63, lo = l & 15, hi = l >> 4;
    const int arow = rb * 64 + w * 16 + lo;            // A-frag row
    const int crow = rb * 64 + w * 16 + hi * 4;        // C-frag base row

    // A frags loaded ONCE (fp32 h -> bf16), reused for all 6 B tiles
    bf16x8 afr[4];
    if (arow < N_NODES) {
        const float* hp = h + (size_t)arow * IN_F;
#pragma unroll
        for (int ks = 0; ks < 4; ++ks) {
            float4 f0 = *(const float4*)(hp + ks * 32 + hi * 8);
            float4 f1 = *(const float4*)(hp + ks * 32 + hi * 8 + 4);
            bf16x8 a;
            a[0]=(bf16)f0.x; a[1]=(bf16)f0.y; a[2]=(bf16)f0.z; a[3]=(bf16)f0.w;
            a[4]=(bf16)f1.x; a[5]=(bf16)f1.y; a[6]=(bf16)f1.z; a[7]=(bf16)f1.w;
            afr[ks] = a;
        }
    } else {
#pragma unroll
        for (int ks = 0; ks < 4; ++ks) { bf16x8 a = {}; afr[ks] = a; }
    }

    for (int p = 0; p < N_PATHS; ++p) {
        __half* feat = featAll + (size_t)p * FEAT_ELEMS;
        const float* alp = al + p * HO;
        const float* arp = ar + p * HO;
        float* elA = elAll + (size_t)p * N_NODES * 4;
        float* erA = erAll + (size_t)p * N_NODES * 4;
#pragma unroll
        for (int ch = 0; ch < 2; ++ch) {
            const bf16* W = fcwT + (size_t)p * 32768 + (size_t)ch * 128 * IN_F;
            f32x4 acc[8];
#pragma unroll
            for (int c = 0; c < 8; ++c) { f32x4 zz = {0.f,0.f,0.f,0.f}; acc[c] = zz; }
#pragma unroll
            for (int ctl = 0; ctl < 8; ++ctl) {
                const bf16* wp = W + (size_t)(ctl * 16 + lo) * IN_F + hi * 8;
                f32x4 a = acc[ctl];
#pragma unroll
                for (int ks = 0; ks < 4; ++ks)
                    a = __builtin_amdgcn_mfma_f32_16x16x32_bf16(afr[ks], *(const bf16x8*)(wp + ks * 32), a, 0, 0, 0);
                acc[ctl] = a;
            }
            // epilogue: fp16 feat store + fused el/er partials
            float elP[2][4] = {{0}}, erP[2][4] = {{0}};
#pragma unroll
            for (int ctl = 0; ctl < 8; ++ctl) {
                const int gcol = ch * 128 + ctl * 16 + lo;
                const float av = alp[gcol], bv = arp[gcol];
                const int hl = ctl >> 2;
#pragma unroll
                for (int rr = 0; rr < 4; ++rr) {
                    float v = acc[ctl][rr];
                    elP[hl][rr] = fmaf(v, av, elP[hl][rr]);
                    erP[hl][rr] = fmaf(v, bv, erP[hl][rr]);
                    if (crow + rr < N_NODES)
                        feat[(size_t)(crow + rr) * HO + gcol] = __float2half(v);
                }
            }
#pragma unroll
            for (int hl = 0; hl < 2; ++hl)
#pragma unroll
                for (int rr = 0; rr < 4; ++rr) {
                    float v = elP[hl][rr], u = erP[hl][rr];
#pragma unroll
                    for (int m = 1; m <= 8; m <<= 1) {
                        v += __shfl_xor(v, m, 64);
                        u += __shfl_xor(u, m, 64);
                    }
                    elP[hl][rr] = v; erP[hl][rr] = u;
                }
            if (lo == 0) {
#pragma unroll
                for (int rr = 0; rr < 4; ++rr) {
                    if (crow + rr < N_NODES) {
                        *(float2*)&elA[(crow + rr) * 4 + ch * 2] = make_float2(elP[0][rr], elP[1][rr]);
                        *(float2*)&erA[(crow + rr) * 4 + ch * 2] = make_float2(erP[0][rr], erP[1][rr]);
                    }
                }
            }
        }
    }
}

// ---- fused: ILP-4 atomic count  CONCURRENT with  MFMA feat -----------------
__global__ __launch_bounds__(256, 4) void k_cf(const int* __restrict__ edges,
                                               int* __restrict__ deg,
                                               u16* __restrict__ rank,
                                               const float* __restrict__ h,
                                               const bf16* __restrict__ fcwT,
                                               const float* __restrict__ al,
                                               const float* __restrict__ ar,
                                               __half* __restrict__ featAll,
                                               float* __restrict__ elAll,
                                               float* __restrict__ erAll) {
    const int bid = blockIdx.x;
    if (bid < CNT_BLOCKS)
        count_role(bid, edges, deg, rank);
    else
        feat_role(bid - CNT_BLOCKS, h, fcwT, al, ar, featAll, elAll, erAll);
}

__global__ __launch_bounds__(1024) void k_scan(const int* __restrict__ deg,
                                               int* __restrict__ rowptr) {
    __shared__ int part[1024];
    const int p = blockIdx.x;
    const int* dg = deg + p * N_NODES;
    int* rp = rowptr + p * (N_NODES + 1);

    const int tid = threadIdx.x;
    const int CH = (N_NODES + 1023) / 1024;       // 49
    const int start = tid * CH;
    int s = 0;
    for (int i = 0; i < CH; ++i) { int idx = start + i; if (idx < N_NODES) s += dg[idx]; }
    part[tid] = s;
    __syncthreads();
    for (int off = 1; off < 1024; off <<= 1) {
        int v = (tid >= off) ? part[tid - off] : 0;
        __syncthreads();
        part[tid] += v;
        __syncthreads();
    }
    int excl = (tid == 0) ? 0 : part[tid - 1];
    for (int i = 0; i < CH; ++i) {
        int idx = start + i;
        if (idx < N_NODES) { rp[idx] = excl; excl += dg[idx]; }
    }
    if (tid == 1023) rp[N_NODES] = N_EDGES;
}

// ---- scatter: 4 edges/thread, atomic-free fire-and-forget ------------------
__global__ __launch_bounds__(256) void k_scatter(const int* __restrict__ edges,
                                                 const u16* __restrict__ rank,
                                                 const int* __restrict__ rowptr,
                                                 u16* __restrict__ csr) {
    int gt = blockIdx.x * 256 + threadIdx.x;
    if (gt >= (N_PATHS * N_EDGES) / 4) return;
    int base = gt * 4;
    int p = base / N_EDGES, e = base - p * N_EDGES;
    const int* ep = edges + (size_t)p * 2 * N_EDGES;
    int4 s4 = *(const int4*)(ep + e);
    int4 d4 = *(const int4*)(ep + N_EDGES + e);
    ushort4 r4 = *(const ushort4*)(rank + base);
    const int* rp = rowptr + p * (N_NODES + 1);
    u16* c = csr + (size_t)p * N_EDGES;
    c[rp[d4.x] + r4.x] = (u16)s4.x;
    c[rp[d4.y] + r4.y] = (u16)s4.y;
    c[rp[d4.z] + r4.z] = (u16)s4.z;
    c[rp[d4.w] + r4.w] = (u16)s4.w;
}

// ---- gather: wave/node, 2 edges/iter (32-lane halves), hfma2, bf16 z -------
__global__ __launch_bounds__(256) void k_gather3(const u16* __restrict__ csrAll,
                                                 const int* __restrict__ rowptrAll,
                                                 const float4* __restrict__ elAll,
                                                 const float4* __restrict__ erAll,
                                                 const __half* __restrict__ featAll,
                                                 bf16* __restrict__ z) {
    __shared__ int     off_lds[4][64];
    __shared__ __half2 a_lds[4][64][4];
    const int pb = blockIdx.x;
    const int p  = pb / (N_NODES / 4);
    const int nb = pb - p * (N_NODES / 4);
    const u16*    csr    = csrAll + (size_t)p * N_EDGES;
    const int*    rowptr = rowptrAll + p * (N_NODES + 1);
    const float4* el4    = elAll + (size_t)p * N_NODES;
    const float4* er4    = erAll + (size_t)p * N_NODES;
    const __half* feat   = featAll + (size_t)p * FEAT_ELEMS;

    const int wid = threadIdx.x >> 6, l = threadIdx.x & 63;
    const int n = nb * 4 + wid;
    const int half = l >> 5, c = l & 31, hh = c >> 3;  // lane covers cols c*8..c*8+7

    const int b0 = rowptr[n], b1 = rowptr[n + 1];
    const float4 er_n = er4[n];

    __half2 acc0 = __float2half2_rn(0.f), acc1 = acc0, acc2 = acc0, acc3 = acc0;
    float4 den = {0.f, 0.f, 0.f, 0.f};

    for (int base = b0; base < b1; base += 64) {
        const int cnt = min(64, b1 - base);
        if (l < cnt) {                                 // stage offsets + alphas (wave-sync)
            int sv = csr[base + l];
            off_lds[wid][l] = sv * HO;
            float4 e = el4[sv];
            float vx = e.x + er_n.x, vy = e.y + er_n.y,
                  vz = e.z + er_n.z, vw = e.w + er_n.w;
            vx = (vx >= 0.f) ? vx : 0.2f * vx;
            vy = (vy >= 0.f) ? vy : 0.2f * vy;
            vz = (vz >= 0.f) ? vz : 0.2f * vz;
            vw = (vw >= 0.f) ? vw : 0.2f * vw;
            float ex = __expf(vx), ey = __expf(vy), ez = __expf(vz), ew = __expf(vw);
            den.x += ex; den.y += ey; den.z += ez; den.w += ew;
            a_lds[wid][l][0] = __float2half2_rn(ex);
            a_lds[wid][l][1] = __float2half2_rn(ey);
            a_lds[wid][l][2] = __float2half2_rn(ez);
            a_lds[wid][l][3] = __float2half2_rn(ew);
        }
        for (int i2 = 0; i2 < cnt; i2 += 2) {          // 2 edges per iter: halves
            const int e = i2 + half;
            if (e < cnt) {
                const int off = off_lds[wid][e];
                const __half2 a2 = a_lds[wid][e][hh];
                const uint4 u = *(const uint4*)(feat + off + c * 8);
                acc0 = __hfma2(__builtin_bit_cast(__half2, u.x), a2, acc0);
                acc1 = __hfma2(__builtin_bit_cast(__half2, u.y), a2, acc1);
                acc2 = __hfma2(__builtin_bit_cast(__half2, u.z), a2, acc2);
                acc3 = __hfma2(__builtin_bit_cast(__half2, u.w), a2, acc3);
            }
        }
    }

    // combine halves + denominator butterfly
    float s[8];
    { float2 f0 = __half22float2(acc0), f1 = __half22float2(acc1),
             f2 = __half22float2(acc2), f3 = __half22float2(acc3);
      s[0]=f0.x; s[1]=f0.y; s[2]=f1.x; s[3]=f1.y; s[4]=f2.x; s[5]=f2.y; s[6]=f3.x; s[7]=f3.y; }
#pragma unroll
    for (int j = 0; j < 8; ++j) s[j] += __shfl_xor(s[j], 32, 64);
#pragma unroll
    for (int off = 32; off; off >>= 1) {
        den.x += __shfl_xor(den.x, off, 64);
        den.y += __shfl_xor(den.y, off, 64);
        den.z += __shfl_xor(den.z, off, 64);
        den.w += __shfl_xor(den.w, off, 64);
    }
    const float d = (hh == 0) ? den.x : (hh == 1) ? den.y : (hh == 2) ? den.z : den.w;
    const float inv = (d > 0.f) ? 1.f / d : 0.f;
    if (half == 0) {
        bf16x8 ov;
#pragma unroll
        for (int j = 0; j < 8; ++j) {
            float v = s[j] * inv;
            v = (v > 0.f) ? v : expm1f(v);             // elu
            ov[j] = (bf16)v;
        }
        *(bf16x8*)(z + (size_t)n * (N_PATHS * HO) + p * HO + c * 8) = ov;
    }
}

// ---- fused semantic attention + output: bf16 LDS, MFMA logits --------------
__global__ __launch_bounds__(256) void k_semout(const bf16* __restrict__ z,
                                                const float* __restrict__ w1,
                                                const float* __restrict__ b1,
                                                const float* __restrict__ w2,
                                                float* __restrict__ out) {
    __shared__ bf16  zs[48 * 264];                     // pad 8: 2-way banks only
    __shared__ float psem[4][48];
    __shared__ float betas[16][4];

    const int t = threadIdx.x, w = t >> 6, l = t & 63;
    const int lo = l & 15, hi = l >> 4;
    const int n0 = blockIdx.x * 16;

    // B-frag preload: wave w covers col-tiles 2w,2w+1
    bf16x8 bfr[2][8];
#pragma unroll
    for (int ct = 0; ct < 2; ++ct) {
        const int j = (2 * w + ct) * 16 + lo;
#pragma unroll
        for (int s = 0; s < 8; ++s) {
            const int k0 = s * 32 + hi * 8;
            bf16x8 b;
#pragma unroll
            for (int i = 0; i < 8; ++i) b[i] = (bf16)w1[(k0 + i) * HID + j];
            bfr[ct][s] = b;
        }
    }

    // stage 48 rows x 256 bf16 (contiguous) into padded LDS
    const uint4* zg4 = (const uint4*)(z + (size_t)n0 * (N_PATHS * HO));
    for (int i = t; i < 1536; i += 256) {
        uint4 v = zg4[i];
        int r = i >> 5, cin = (i & 31) * 8;
        *(uint4*)&zs[r * 264 + cin] = v;
    }
    __syncthreads();

    f32x4 acc[2][3];
#pragma unroll
    for (int ct = 0; ct < 2; ++ct)
#pragma unroll
        for (int m = 0; m < 3; ++m) { f32x4 zz = {0.f,0.f,0.f,0.f}; acc[ct][m] = zz; }

    for (int s = 0; s < 8; ++s) {
#pragma unroll
        for (int m = 0; m < 3; ++m) {
            bf16x8 a = *(const bf16x8*)&zs[(m * 16 + lo) * 264 + s * 32 + hi * 8];
            acc[0][m] = __builtin_amdgcn_mfma_f32_16x16x32_bf16(a, bfr[0][s], acc[0][m], 0, 0, 0);
            acc[1][m] = __builtin_amdgcn_mfma_f32_16x16x32_bf16(a, bfr[1][s], acc[1][m], 0, 0, 0);
        }
    }

    const int j0 = (2 * w + 0) * 16 + lo;
    const int j1 = (2 * w + 1) * 16 + lo;
    const float b1_0 = b1[j0], w2_0 = w2[j0];
    const float b1_1 = b1[j1], w2_1 = w2[j1];
#pragma unroll
    for (int m = 0; m < 3; ++m) {
#pragma unroll
        for (int r = 0; r < 4; ++r) {
            float tt = tanhf(acc[0][m][r] + b1_0) * w2_0
                     + tanhf(acc[1][m][r] + b1_1) * w2_1;
            tt += __shfl_xor(tt, 1, 64);
            tt += __shfl_xor(tt, 2, 64);
            tt += __shfl_xor(tt, 4, 64);
            tt += __shfl_xor(tt, 8, 64);
            if (lo == 0) psem[w][m * 16 + hi * 4 + r] = tt;
        }
    }
    __syncthreads();
    if (t < 48) psem[0][t] = psem[0][t] + psem[1][t] + psem[2][t] + psem[3][t];
    __syncthreads();
    if (t < 16) {
        float a0 = psem[0][3 * t], a1 = psem[0][3 * t + 1], a2 = psem[0][3 * t + 2];
        float mx = fmaxf(a0, fmaxf(a1, a2));
        float e0 = __expf(a0 - mx), e1 = __expf(a1 - mx), e2 = __expf(a2 - mx);
        float is = 1.f / (e0 + e1 + e2);
        betas[t][0] = e0 * is; betas[t][1] = e1 * is; betas[t][2] = e2 * is;
    }
    __syncthreads();
    for (int i = 0; i < 16; ++i) {
        float bb0 = betas[i][0], bb1 = betas[i][1], bb2 = betas[i][2];
        float o = bb0 * (float)zs[(3 * i + 0) * 264 + t]
                + bb1 * (float)zs[(3 * i + 1) * 264 + t]
                + bb2 * (float)zs[(3 * i + 2) * 264 + t];
        out[(size_t)(n0 + i) * HO + t] = o;
    }
}

// ---------------------------------------------------------------------------
static inline size_t align256(size_t x) { return (x + 255) & ~(size_t)255; }

extern "C" void kernel_launch(void* const* d_in, const int* in_sizes, int n_in,
                              void* d_out, int out_size, void* d_ws, size_t ws_size,
                              hipStream_t stream) {
    const float* h     = (const float*)d_in[0];
    const int*   edges = (const int*)d_in[1];     // [P,2,E]
    const float* fc_w  = (const float*)d_in[2];   // [P,128,256]
    const float* al    = (const float*)d_in[3];   // [P,4,64]
    const float* ar    = (const float*)d_in[4];
    const float* w1    = (const float*)d_in[5];   // [256,128]
    const float* b1    = (const float*)d_in[6];   // [128]
    const float* w2    = (const float*)d_in[7];   // [128]
    float* out = (float*)d_out;

    char* base = (char*)d_ws;
    size_t off = 0;
    auto carve = [&](size_t bytes) -> char* {
        char* p = base + off; off = align256(off + bytes); return p;
    };
    bf16*   zbuf   = (bf16*)carve((size_t)N_NODES * N_PATHS * HO * 2);   // 76.8 MB
    __half* feat   = (__half*)carve((size_t)N_PATHS * FEAT_ELEMS * 2);   // 76.8 MB
    bf16*   fcwT   = (bf16*)carve((size_t)N_PATHS * IN_F * HO * 2);      // 192 KB
    float*  el     = (float*)carve((size_t)N_PATHS * N_NODES * 4 * 4);   // 2.4 MB
    float*  er     = (float*)carve((size_t)N_PATHS * N_NODES * 4 * 4);   // 2.4 MB
    int*    deg    = (int*)carve((size_t)N_PATHS * N_NODES * 4);
    int*    rowptr = (int*)carve((size_t)N_PATHS * (N_NODES + 1) * 4);
    u16*    rank   = (u16*)carve((size_t)N_PATHS * N_EDGES * 2);         // 4.8 MB
    u16*    csr    = (u16*)carve((size_t)N_PATHS * N_EDGES * 2);         // 4.8 MB
    (void)ws_size; (void)in_sizes; (void)n_in; (void)out_size;

    k_prep<<<PREP_T_BLOCKS + PREP_Z_BLOCKS, 256, 0, stream>>>(fc_w, fcwT, deg);
    // atomic count (latency-bound) overlapped with all 3 MFMA feat GEMMs
    k_cf<<<CNT_BLOCKS + FEAT_RB, 256, 0, stream>>>(
        edges, deg, rank, h, fcwT, al, ar, feat, el, er);
    k_scan<<<N_PATHS, 1024, 0, stream>>>(deg, rowptr);
    k_scatter<<<SCAT_BLOCKS, 256, 0, stream>>>(edges, rank, rowptr, csr);
    k_gather3<<<N_PATHS * (N_NODES / 4), 256, 0, stream>>>(
        csr, rowptr, (const float4*)el, (const float4*)er, feat, zbuf);
    k_semout<<<N_NODES / 16, 256, 0, stream>>>(zbuf, w1, b1, w2, out);
}

// Round 7
// 492.291 us; speedup vs baseline: 4.2070x; 1.1341x over previous
//
#include <hip/hip_runtime.h>
#include <hip/hip_bf16.h>
#include <hip/hip_fp16.h>

#define N_NODES 50000
#define N_EDGES 800000
#define N_PATHS 3
#define IN_F    128
#define HO      256   // H*OUT
#define N_HEADS 4
#define HID     128

#define BLK_PER_PATH 32
#define EDGES_PER_HB 25000                      // N_EDGES / BLK_PER_PATH
#define HIST_BLOCKS  (N_PATHS * BLK_PER_PATH)   // 96
#define NPACK        12500                      // N_NODES/4 nodes per packed u32
#define FEAT_RB      782                        // ceil(50000/64)
#define SCAT_BLOCKS  2344                       // 2.4M edges / (256*4)
#define FEAT_ELEMS   ((size_t)N_NODES * HO)

typedef __bf16 bf16;
typedef __bf16 bf16x8 __attribute__((ext_vector_type(8)));
typedef float  f32x4  __attribute__((ext_vector_type(4)));
typedef unsigned short u16;
typedef unsigned char  u8;
typedef unsigned int   u32;

// ---- prep: fcwT[p][col][k] bf16 transpose ----------------------------------
__global__ __launch_bounds__(256) void k_prep(const float* __restrict__ fc_w,
                                              bf16* __restrict__ fcwT) {
    int g = blockIdx.x * 256 + threadIdx.x;          // < 98304
    int p = g >> 15, r = g & 32767;
    int col = r & 255, k = r >> 8;
    fcwT[(size_t)p * 32768 + col * IN_F + k] = (bf16)fc_w[(size_t)p * 32768 + k * HO + col];
}

// ---- hist: LDS histogram (4x u8 packed) + per-edge local rank, NO global atomics
__global__ __launch_bounds__(256) void k_hist(const int* __restrict__ edges,
                                              u32* __restrict__ cnt32,
                                              u8* __restrict__ lrank) {
    __shared__ u32 hist[NPACK];                      // 50 KB
    const int b = blockIdx.x;
    const int p = b / BLK_PER_PATH, blk = b - p * BLK_PER_PATH;
    const int t = threadIdx.x;
    for (int i = t; i < NPACK; i += 256) hist[i] = 0;
    __syncthreads();

    const int* dstp = edges + (size_t)p * 2 * N_EDGES + N_EDGES + blk * EDGES_PER_HB;
    u8* lr = lrank + (size_t)p * N_EDGES + blk * EDGES_PER_HB;
    for (int q = t; q < EDGES_PER_HB / 4; q += 256) {
        int4 d4 = ((const int4*)dstp)[q];
        u32 o0 = atomicAdd(&hist[d4.x >> 2], 1u << ((d4.x & 3) * 8));
        u32 o1 = atomicAdd(&hist[d4.y >> 2], 1u << ((d4.y & 3) * 8));
        u32 o2 = atomicAdd(&hist[d4.z >> 2], 1u << ((d4.z & 3) * 8));
        u32 o3 = atomicAdd(&hist[d4.w >> 2], 1u << ((d4.w & 3) * 8));
        uchar4 r4;
        r4.x = (u8)(o0 >> ((d4.x & 3) * 8));
        r4.y = (u8)(o1 >> ((d4.y & 3) * 8));
        r4.z = (u8)(o2 >> ((d4.z & 3) * 8));
        r4.w = (u8)(o3 >> ((d4.w & 3) * 8));
        ((uchar4*)lr)[q] = r4;
    }
    __syncthreads();
    u32* out = cnt32 + (size_t)b * NPACK;
    for (int i = t; i < NPACK; i += 256) out[i] = hist[i];
}

// ---- base: per-node prefix over the 32 block counts (in place) + deg -------
__global__ __launch_bounds__(256) void k_base(u32* __restrict__ cnt32,
                                              int* __restrict__ deg) {
    int g = blockIdx.x * 256 + threadIdx.x;          // node-quad id
    if (g >= N_PATHS * NPACK) return;
    int p = g / NPACK, q = g - p * NPACK;
    u32 s0 = 0, s1 = 0, s2 = 0, s3 = 0;
#pragma unroll
    for (int blk = 0; blk < BLK_PER_PATH; ++blk) {
        size_t idx = (size_t)(p * BLK_PER_PATH + blk) * NPACK + q;
        u32 c = cnt32[idx];
        cnt32[idx] = s0 | (s1 << 8) | (s2 << 16) | (s3 << 24);  // bases (u8 each)
        s0 += c & 0xff; s1 += (c >> 8) & 0xff; s2 += (c >> 16) & 0xff; s3 += c >> 24;
    }
    int4 d4 = {(int)s0, (int)s1, (int)s2, (int)s3};
    *(int4*)(deg + (size_t)p * N_NODES + 4 * q) = d4;
}

__global__ __launch_bounds__(1024) void k_scan(const int* __restrict__ deg,
                                               int* __restrict__ rowptr) {
    __shared__ int part[1024];
    const int p = blockIdx.x;
    const int* dg = deg + p * N_NODES;
    int* rp = rowptr + p * (N_NODES + 1);

    const int tid = threadIdx.x;
    const int CH = (N_NODES + 1023) / 1024;       // 49
    const int start = tid * CH;
    int s = 0;
    for (int i = 0; i < CH; ++i) { int idx = start + i; if (idx < N_NODES) s += dg[idx]; }
    part[tid] = s;
    __syncthreads();
    for (int off = 1; off < 1024; off <<= 1) {
        int v = (tid >= off) ? part[tid - off] : 0;
        __syncthreads();
        part[tid] += v;
        __syncthreads();
    }
    int excl = (tid == 0) ? 0 : part[tid - 1];
    for (int i = 0; i < CH; ++i) {
        int idx = start + i;
        if (idx < N_NODES) { rp[idx] = excl; excl += dg[idx]; }
    }
    if (tid == 1023) rp[N_NODES] = N_EDGES;
}

// ---- scatter role: atomic-free, 4 edges/thread -----------------------------
__device__ __forceinline__ void scatter_role(int b, const int* __restrict__ edges,
                                             const u8* __restrict__ lrank,
                                             const u32* __restrict__ cnt32,
                                             const int* __restrict__ rowptr,
                                             u16* __restrict__ csr) {
    int gt = b * 256 + threadIdx.x;
    if (gt >= (N_PATHS * N_EDGES) / 4) return;
    int base = gt * 4;
    int p = base / N_EDGES, e = base - p * N_EDGES;
    const int blk = e / EDGES_PER_HB;                // quad never crosses chunk
    const int* ep = edges + (size_t)p * 2 * N_EDGES;
    int4 s4 = *(const int4*)(ep + e);
    int4 d4 = *(const int4*)(ep + N_EDGES + e);
    uchar4 r4 = *(const uchar4*)(lrank + base);
    const int* rp = rowptr + p * (N_NODES + 1);
    const u32* bb = cnt32 + (size_t)(p * BLK_PER_PATH + blk) * NPACK;
    u16* c = csr + (size_t)p * N_EDGES;
    int p0 = rp[d4.x] + ((bb[d4.x >> 2] >> ((d4.x & 3) * 8)) & 0xff) + r4.x;
    int p1 = rp[d4.y] + ((bb[d4.y >> 2] >> ((d4.y & 3) * 8)) & 0xff) + r4.y;
    int p2 = rp[d4.z] + ((bb[d4.z >> 2] >> ((d4.z & 3) * 8)) & 0xff) + r4.z;
    int p3 = rp[d4.w] + ((bb[d4.w >> 2] >> ((d4.w & 3) * 8)) & 0xff) + r4.w;
    c[p0] = (u16)s4.x; c[p1] = (u16)s4.y; c[p2] = (u16)s4.z; c[p3] = (u16)s4.w;
}

// ---- fat feat role: one 64-row block does all 3 paths x 2 col-halves -------
__device__ __forceinline__ void feat_role(int rb, const float* __restrict__ h,
                                          const bf16* __restrict__ fcwT,
                                          const float* __restrict__ al,
                                          const float* __restrict__ ar,
                                          __half* __restrict__ featAll,
                                          float* __restrict__ elAll,
                                          float* __restrict__ erAll) {
    const int t = threadIdx.x, w = t >> 6, l = t & 63, lo = l & 15, hi = l >> 4;
    const int arow = rb * 64 + w * 16 + lo;
    const int crow = rb * 64 + w * 16 + hi * 4;

    bf16x8 afr[4];
    if (arow < N_NODES) {
        const float* hp = h + (size_t)arow * IN_F;
#pragma unroll
        for (int ks = 0; ks < 4; ++ks) {
            float4 f0 = *(const float4*)(hp + ks * 32 + hi * 8);
            float4 f1 = *(const float4*)(hp + ks * 32 + hi * 8 + 4);
            bf16x8 a;
            a[0]=(bf16)f0.x; a[1]=(bf16)f0.y; a[2]=(bf16)f0.z; a[3]=(bf16)f0.w;
            a[4]=(bf16)f1.x; a[5]=(bf16)f1.y; a[6]=(bf16)f1.z; a[7]=(bf16)f1.w;
            afr[ks] = a;
        }
    } else {
#pragma unroll
        for (int ks = 0; ks < 4; ++ks) { bf16x8 a = {}; afr[ks] = a; }
    }

    for (int p = 0; p < N_PATHS; ++p) {
        __half* feat = featAll + (size_t)p * FEAT_ELEMS;
        const float* alp = al + p * HO;
        const float* arp = ar + p * HO;
        float* elA = elAll + (size_t)p * N_NODES * 4;
        float* erA = erAll + (size_t)p * N_NODES * 4;
#pragma unroll
        for (int ch = 0; ch < 2; ++ch) {
            const bf16* W = fcwT + (size_t)p * 32768 + (size_t)ch * 128 * IN_F;
            f32x4 acc[8];
#pragma unroll
            for (int c = 0; c < 8; ++c) { f32x4 zz = {0.f,0.f,0.f,0.f}; acc[c] = zz; }
#pragma unroll
            for (int ctl = 0; ctl < 8; ++ctl) {
                const bf16* wp = W + (size_t)(ctl * 16 + lo) * IN_F + hi * 8;
                f32x4 a = acc[ctl];
#pragma unroll
                for (int ks = 0; ks < 4; ++ks)
                    a = __builtin_amdgcn_mfma_f32_16x16x32_bf16(afr[ks], *(const bf16x8*)(wp + ks * 32), a, 0, 0, 0);
                acc[ctl] = a;
            }
            float elP[2][4] = {{0}}, erP[2][4] = {{0}};
#pragma unroll
            for (int ctl = 0; ctl < 8; ++ctl) {
                const int gcol = ch * 128 + ctl * 16 + lo;
                const float av = alp[gcol], bv = arp[gcol];
                const int hl = ctl >> 2;
#pragma unroll
                for (int rr = 0; rr < 4; ++rr) {
                    float v = acc[ctl][rr];
                    elP[hl][rr] = fmaf(v, av, elP[hl][rr]);
                    erP[hl][rr] = fmaf(v, bv, erP[hl][rr]);
                    if (crow + rr < N_NODES)
                        feat[(size_t)(crow + rr) * HO + gcol] = __float2half(v);
                }
            }
#pragma unroll
            for (int hl = 0; hl < 2; ++hl)
#pragma unroll
                for (int rr = 0; rr < 4; ++rr) {
                    float v = elP[hl][rr], u = erP[hl][rr];
#pragma unroll
                    for (int m = 1; m <= 8; m <<= 1) {
                        v += __shfl_xor(v, m, 64);
                        u += __shfl_xor(u, m, 64);
                    }
                    elP[hl][rr] = v; erP[hl][rr] = u;
                }
            if (lo == 0) {
#pragma unroll
                for (int rr = 0; rr < 4; ++rr) {
                    if (crow + rr < N_NODES) {
                        *(float2*)&elA[(crow + rr) * 4 + ch * 2] = make_float2(elP[0][rr], elP[1][rr]);
                        *(float2*)&erA[(crow + rr) * 4 + ch * 2] = make_float2(erP[0][rr], erP[1][rr]);
                    }
                }
            }
        }
    }
}

// ---- fused: atomic-free scatter CONCURRENT with MFMA feat ------------------
__global__ __launch_bounds__(256, 4) void k_fs(const int* __restrict__ edges,
                                               const u8* __restrict__ lrank,
                                               const u32* __restrict__ cnt32,
                                               const int* __restrict__ rowptr,
                                               u16* __restrict__ csr,
                                               const float* __restrict__ h,
                                               const bf16* __restrict__ fcwT,
                                               const float* __restrict__ al,
                                               const float* __restrict__ ar,
                                               __half* __restrict__ featAll,
                                               float* __restrict__ elAll,
                                               float* __restrict__ erAll) {
    const int bid = blockIdx.x;
    if (bid < SCAT_BLOCKS)
        scatter_role(bid, edges, lrank, cnt32, rowptr, csr);
    else
        feat_role(bid - SCAT_BLOCKS, h, fcwT, al, ar, featAll, elAll, erAll);
}

// ---- gather: wave/node, 2 edges/iter (32-lane halves), hfma2, bf16 z -------
__global__ __launch_bounds__(256) void k_gather3(const u16* __restrict__ csrAll,
                                                 const int* __restrict__ rowptrAll,
                                                 const float4* __restrict__ elAll,
                                                 const float4* __restrict__ erAll,
                                                 const __half* __restrict__ featAll,
                                                 bf16* __restrict__ z) {
    __shared__ int     off_lds[4][64];
    __shared__ __half2 a_lds[4][64][4];
    const int pb = blockIdx.x;
    const int p  = pb / (N_NODES / 4);
    const int nb = pb - p * (N_NODES / 4);
    const u16*    csr    = csrAll + (size_t)p * N_EDGES;
    const int*    rowptr = rowptrAll + p * (N_NODES + 1);
    const float4* el4    = elAll + (size_t)p * N_NODES;
    const float4* er4    = erAll + (size_t)p * N_NODES;
    const __half* feat   = featAll + (size_t)p * FEAT_ELEMS;

    const int wid = threadIdx.x >> 6, l = threadIdx.x & 63;
    const int n = nb * 4 + wid;
    const int half = l >> 5, c = l & 31, hh = c >> 3;

    const int b0 = rowptr[n], b1 = rowptr[n + 1];
    const float4 er_n = er4[n];

    __half2 acc0 = __float2half2_rn(0.f), acc1 = acc0, acc2 = acc0, acc3 = acc0;
    float4 den = {0.f, 0.f, 0.f, 0.f};

    for (int base = b0; base < b1; base += 64) {
        const int cnt = min(64, b1 - base);
        if (l < cnt) {
            int sv = csr[base + l];
            off_lds[wid][l] = sv * HO;
            float4 e = el4[sv];
            float vx = e.x + er_n.x, vy = e.y + er_n.y,
                  vz = e.z + er_n.z, vw = e.w + er_n.w;
            vx = (vx >= 0.f) ? vx : 0.2f * vx;
            vy = (vy >= 0.f) ? vy : 0.2f * vy;
            vz = (vz >= 0.f) ? vz : 0.2f * vz;
            vw = (vw >= 0.f) ? vw : 0.2f * vw;
            float ex = __expf(vx), ey = __expf(vy), ez = __expf(vz), ew = __expf(vw);
            den.x += ex; den.y += ey; den.z += ez; den.w += ew;
            a_lds[wid][l][0] = __float2half2_rn(ex);
            a_lds[wid][l][1] = __float2half2_rn(ey);
            a_lds[wid][l][2] = __float2half2_rn(ez);
            a_lds[wid][l][3] = __float2half2_rn(ew);
        }
        for (int i2 = 0; i2 < cnt; i2 += 2) {
            const int e = i2 + half;
            if (e < cnt) {
                const int off = off_lds[wid][e];
                const __half2 a2 = a_lds[wid][e][hh];
                const uint4 u = *(const uint4*)(feat + off + c * 8);
                acc0 = __hfma2(__builtin_bit_cast(__half2, u.x), a2, acc0);
                acc1 = __hfma2(__builtin_bit_cast(__half2, u.y), a2, acc1);
                acc2 = __hfma2(__builtin_bit_cast(__half2, u.z), a2, acc2);
                acc3 = __hfma2(__builtin_bit_cast(__half2, u.w), a2, acc3);
            }
        }
    }

    float s[8];
    { float2 f0 = __half22float2(acc0), f1 = __half22float2(acc1),
             f2 = __half22float2(acc2), f3 = __half22float2(acc3);
      s[0]=f0.x; s[1]=f0.y; s[2]=f1.x; s[3]=f1.y; s[4]=f2.x; s[5]=f2.y; s[6]=f3.x; s[7]=f3.y; }
#pragma unroll
    for (int j = 0; j < 8; ++j) s[j] += __shfl_xor(s[j], 32, 64);
#pragma unroll
    for (int off = 32; off; off >>= 1) {
        den.x += __shfl_xor(den.x, off, 64);
        den.y += __shfl_xor(den.y, off, 64);
        den.z += __shfl_xor(den.z, off, 64);
        den.w += __shfl_xor(den.w, off, 64);
    }
    const float d = (hh == 0) ? den.x : (hh == 1) ? den.y : (hh == 2) ? den.z : den.w;
    const float inv = (d > 0.f) ? 1.f / d : 0.f;
    if (half == 0) {
        bf16x8 ov;
#pragma unroll
        for (int j = 0; j < 8; ++j) {
            float v = s[j] * inv;
            v = (v > 0.f) ? v : expm1f(v);
            ov[j] = (bf16)v;
        }
        *(bf16x8*)(z + (size_t)n * (N_PATHS * HO) + p * HO + c * 8) = ov;
    }
}

// ---- fused semantic attention + output: bf16 LDS, MFMA logits --------------
__global__ __launch_bounds__(256) void k_semout(const bf16* __restrict__ z,
                                                const float* __restrict__ w1,
                                                const float* __restrict__ b1,
                                                const float* __restrict__ w2,
                                                float* __restrict__ out) {
    __shared__ bf16  zs[48 * 264];
    __shared__ float psem[4][48];
    __shared__ float betas[16][4];

    const int t = threadIdx.x, w = t >> 6, l = t & 63;
    const int lo = l & 15, hi = l >> 4;
    const int n0 = blockIdx.x * 16;

    bf16x8 bfr[2][8];
#pragma unroll
    for (int ct = 0; ct < 2; ++ct) {
        const int j = (2 * w + ct) * 16 + lo;
#pragma unroll
        for (int s = 0; s < 8; ++s) {
            const int k0 = s * 32 + hi * 8;
            bf16x8 b;
#pragma unroll
            for (int i = 0; i < 8; ++i) b[i] = (bf16)w1[(k0 + i) * HID + j];
            bfr[ct][s] = b;
        }
    }

    const uint4* zg4 = (const uint4*)(z + (size_t)n0 * (N_PATHS * HO));
    for (int i = t; i < 1536; i += 256) {
        uint4 v = zg4[i];
        int r = i >> 5, cin = (i & 31) * 8;
        *(uint4*)&zs[r * 264 + cin] = v;
    }
    __syncthreads();

    f32x4 acc[2][3];
#pragma unroll
    for (int ct = 0; ct < 2; ++ct)
#pragma unroll
        for (int m = 0; m < 3; ++m) { f32x4 zz = {0.f,0.f,0.f,0.f}; acc[ct][m] = zz; }

    for (int s = 0; s < 8; ++s) {
#pragma unroll
        for (int m = 0; m < 3; ++m) {
            bf16x8 a = *(const bf16x8*)&zs[(m * 16 + lo) * 264 + s * 32 + hi * 8];
            acc[0][m] = __builtin_amdgcn_mfma_f32_16x16x32_bf16(a, bfr[0][s], acc[0][m], 0, 0, 0);
            acc[1][m] = __builtin_amdgcn_mfma_f32_16x16x32_bf16(a, bfr[1][s], acc[1][m], 0, 0, 0);
        }
    }

    const int j0 = (2 * w + 0) * 16 + lo;
    const int j1 = (2 * w + 1) * 16 + lo;
    const float b1_0 = b1[j0], w2_0 = w2[j0];
    const float b1_1 = b1[j1], w2_1 = w2[j1];
#pragma unroll
    for (int m = 0; m < 3; ++m) {
#pragma unroll
        for (int r = 0; r < 4; ++r) {
            float tt = tanhf(acc[0][m][r] + b1_0) * w2_0
                     + tanhf(acc[1][m][r] + b1_1) * w2_1;
            tt += __shfl_xor(tt, 1, 64);
            tt += __shfl_xor(tt, 2, 64);
            tt += __shfl_xor(tt, 4, 64);
            tt += __shfl_xor(tt, 8, 64);
            if (lo == 0) psem[w][m * 16 + hi * 4 + r] = tt;
        }
    }
    __syncthreads();
    if (t < 48) psem[0][t] = psem[0][t] + psem[1][t] + psem[2][t] + psem[3][t];
    __syncthreads();
    if (t < 16) {
        float a0 = psem[0][3 * t], a1 = psem[0][3 * t + 1], a2 = psem[0][3 * t + 2];
        float mx = fmaxf(a0, fmaxf(a1, a2));
        float e0 = __expf(a0 - mx), e1 = __expf(a1 - mx), e2 = __expf(a2 - mx);
        float is = 1.f / (e0 + e1 + e2);
        betas[t][0] = e0 * is; betas[t][1] = e1 * is; betas[t][2] = e2 * is;
    }
    __syncthreads();
    for (int i = 0; i < 16; ++i) {
        float bb0 = betas[i][0], bb1 = betas[i][1], bb2 = betas[i][2];
        float o = bb0 * (float)zs[(3 * i + 0) * 264 + t]
                + bb1 * (float)zs[(3 * i + 1) * 264 + t]
                + bb2 * (float)zs[(3 * i + 2) * 264 + t];
        out[(size_t)(n0 + i) * HO + t] = o;
    }
}

// ---------------------------------------------------------------------------
static inline size_t align256(size_t x) { return (x + 255) & ~(size_t)255; }

extern "C" void kernel_launch(void* const* d_in, const int* in_sizes, int n_in,
                              void* d_out, int out_size, void* d_ws, size_t ws_size,
                              hipStream_t stream) {
    const float* h     = (const float*)d_in[0];
    const int*   edges = (const int*)d_in[1];     // [P,2,E]
    const float* fc_w  = (const float*)d_in[2];   // [P,128,256]
    const float* al    = (const float*)d_in[3];   // [P,4,64]
    const float* ar    = (const float*)d_in[4];
    const float* w1    = (const float*)d_in[5];   // [256,128]
    const float* b1    = (const float*)d_in[6];   // [128]
    const float* w2    = (const float*)d_in[7];   // [128]
    float* out = (float*)d_out;

    char* base = (char*)d_ws;
    size_t off = 0;
    auto carve = [&](size_t bytes) -> char* {
        char* p = base + off; off = align256(off + bytes); return p;
    };
    bf16*   zbuf   = (bf16*)carve((size_t)N_NODES * N_PATHS * HO * 2);   // 76.8 MB
    __half* feat   = (__half*)carve((size_t)N_PATHS * FEAT_ELEMS * 2);   // 76.8 MB
    bf16*   fcwT   = (bf16*)carve((size_t)N_PATHS * IN_F * HO * 2);      // 192 KB
    float*  el     = (float*)carve((size_t)N_PATHS * N_NODES * 4 * 4);   // 2.4 MB
    float*  er     = (float*)carve((size_t)N_PATHS * N_NODES * 4 * 4);   // 2.4 MB
    int*    deg    = (int*)carve((size_t)N_PATHS * N_NODES * 4);         // 0.6 MB
    int*    rowptr = (int*)carve((size_t)N_PATHS * (N_NODES + 1) * 4);   // 0.6 MB
    u8*     lrank  = (u8*)carve((size_t)N_PATHS * N_EDGES);              // 2.4 MB
    u16*    csr    = (u16*)carve((size_t)N_PATHS * N_EDGES * 2);         // 4.8 MB
    u32*    cnt32  = (u32*)carve((size_t)HIST_BLOCKS * NPACK * 4);       // 4.8 MB
    (void)ws_size; (void)in_sizes; (void)n_in; (void)out_size;

    k_prep<<<384, 256, 0, stream>>>(fc_w, fcwT);
    k_hist<<<HIST_BLOCKS, 256, 0, stream>>>(edges, cnt32, lrank);
    k_base<<<(N_PATHS * NPACK + 255) / 256, 256, 0, stream>>>(cnt32, deg);
    k_scan<<<N_PATHS, 1024, 0, stream>>>(deg, rowptr);
    // atomic-free scatter overlapped with all 3 MFMA feat GEMMs
    k_fs<<<SCAT_BLOCKS + FEAT_RB, 256, 0, stream>>>(
        edges, lrank, cnt32, rowptr, csr, h, fcwT, al, ar, feat, el, er);
    k_gather3<<<N_PATHS * (N_NODES / 4), 256, 0, stream>>>(
        csr, rowptr, (const float4*)el, (const float4*)er, feat, zbuf);
    k_semout<<<N_NODES / 16, 256, 0, stream>>>(zbuf, w1, b1, w2, out);
}